// Round 6
// baseline (594.467 us; speedup 1.0000x reference)
//
#include <hip/hip_runtime.h>

// Problem constants
#define NB 16
#define NH 64
#define NW 64
#define ND 128
#define NK 4096
#define NROWS (NB * NH * NW)        // 65536
#define NSLICE 4
#define SLICE_K (NK / NSLICE)       // 1024
#define OUT_ELEMS (NB * ND * NH * NW)  // 8388608
// fp16 single-term fast path: score-gap error sigma ~= 0.013 (see journal);
// margin 0.10 ~= 8 sigma. Rescue handles everything below it exactly.
#define MARGIN_F 0.10f

typedef _Float16 f16x8 __attribute__((ext_vector_type(8)));
typedef float f32x4 __attribute__((ext_vector_type(4)));

__device__ __forceinline__ unsigned short f2h(float x) {
    _Float16 h = (_Float16)x;              // v_cvt_f16_f32, RNE
    return __builtin_bit_cast(unsigned short, h);
}
// Order-preserving (score,idx) packing: smaller score first, then smaller idx.
__device__ __forceinline__ unsigned long long pack_si(float s, int idx) {
    unsigned int u = __float_as_uint(s);
    unsigned int key = ((int)u < 0) ? ~u : (u | 0x80000000u);
    return ((unsigned long long)key << 32) | (unsigned int)idx;
}

// ---------------------------------------------------------------------------
// Kernel 1: emb prep — enorm (fp32 exact) + fp16 codebook e_h.
// ---------------------------------------------------------------------------
__global__ void emb_prep_kernel(const float* __restrict__ emb,
                                float* __restrict__ enorm,
                                unsigned short* __restrict__ e_h) {
    int wave = (blockIdx.x * blockDim.x + threadIdx.x) >> 6;
    int lane = threadIdx.x & 63;
    if (wave >= NK) return;
    const float* e = emb + (size_t)wave * ND;
    float a = e[lane];
    float b = e[lane + 64];
    e_h[(size_t)wave * ND + lane] = f2h(a);
    e_h[(size_t)wave * ND + lane + 64] = f2h(b);
    float s = a * a + b * b;
#pragma unroll
    for (int off = 32; off > 0; off >>= 1) s += __shfl_down(s, off, 64);
    if (lane == 0) enorm[wave] = s;
}

// ---------------------------------------------------------------------------
// Kernel 2: MFMA argmin. fp16 single-MFMA fast path.
// Occupancy history: (2,2) = 225us, Occ 22.7%, latency-bound, no pipe >30%.
// (4,4) REGRESSED to 358us: min=4 forced a 128-reg budget, compiler split
// 64 arch + 64 acc -> arch side spilled (FETCH 20MB->802MB of scratch).
// (3,4): min=3 gives a 170-reg budget (no spill possible at natural 120),
// max=4 lets HW schedule 4 waves/SIMD if the 128-granule alloc fits.
// ---------------------------------------------------------------------------
#define ZST 136   // LDS row stride in ushort

__global__ void
__attribute__((amdgpu_flat_work_group_size(256, 256), amdgpu_waves_per_eu(3, 4)))
mfma_argmin_kernel(const float* __restrict__ z,
                   const unsigned short* __restrict__ e_h,
                   const float* __restrict__ enorm,
                   int* __restrict__ idx_out,
                   int* __restrict__ rcount,
                   int* __restrict__ rlist,
                   unsigned long long* __restrict__ rpart) {
    __shared__ unsigned short zh[64 * ZST];
    __shared__ float redb1[NSLICE * 64];
    __shared__ float redb2[NSLICE * 64];
    __shared__ int redi1[NSLICE * 64];

    const int bid = blockIdx.x;
    const int rowbase = bid * 64;
    const int t = threadIdx.x;

    const float4* zg = (const float4*)(z + (size_t)rowbase * ND);
#pragma unroll
    for (int q = 0; q < 8; q++) {
        int i = t + 256 * q;               // 0..2047
        float4 v = zg[i];
        int r = i >> 5;
        int c4 = (i & 31) << 2;
        ushort4 hv = make_ushort4(f2h(v.x), f2h(v.y), f2h(v.z), f2h(v.w));
        *(ushort4*)&zh[r * ZST + c4] = hv;
    }
    __syncthreads();

    const int lane = t & 63;
    const int wid = __builtin_amdgcn_readfirstlane(t >> 6);
    const int quad = lane >> 4;
    const int c = lane & 15;
    const int n0 = wid * SLICE_K;

    float b1[4][4], b2[4][4];
    int i1[4][4];
#pragma unroll
    for (int mi = 0; mi < 4; mi++)
#pragma unroll
        for (int r = 0; r < 4; r++) { b1[mi][r] = 3.4e38f; b2[mi][r] = 3.4e38f; i1[mi][r] = 0; }

    const int aoff = c * ZST + quad * 8;
    const unsigned short* pbh = e_h + c * ND + quad * 8;

    for (int nb = n0; nb < n0 + SLICE_K; nb += 64) {
        f32x4 acc[4][4];
#pragma unroll
        for (int mi = 0; mi < 4; mi++)
#pragma unroll
            for (int ni = 0; ni < 4; ni++) acc[mi][ni] = (f32x4){0.f, 0.f, 0.f, 0.f};

#pragma unroll
        for (int kk = 0; kk < 4; kk++) {
            f16x8 ah[4];
#pragma unroll
            for (int mi = 0; mi < 4; mi++)
                ah[mi] = *(const f16x8*)&zh[aoff + mi * (16 * ZST) + kk * 32];
#pragma unroll
            for (int ni = 0; ni < 4; ni++) {
                size_t boff = (size_t)(nb + ni * 16) * ND + kk * 32;
                f16x8 bhv = *(const f16x8*)(pbh + boff);
#pragma unroll
                for (int mi = 0; mi < 4; mi++)
                    acc[mi][ni] = __builtin_amdgcn_mfma_f32_16x16x32_f16(ah[mi], bhv, acc[mi][ni], 0, 0, 0);
            }
        }

#pragma unroll
        for (int ni = 0; ni < 4; ni++) {
            int n = nb + ni * 16 + c;
            float en = enorm[n];
#pragma unroll
            for (int mi = 0; mi < 4; mi++)
#pragma unroll
                for (int r = 0; r < 4; r++) {
                    float s = fmaf(-2.0f, acc[mi][ni][r], en);
                    if (s < b1[mi][r]) { b2[mi][r] = b1[mi][r]; b1[mi][r] = s; i1[mi][r] = n; }
                    else if (s < b2[mi][r]) b2[mi][r] = s;
                }
        }
    }

#pragma unroll
    for (int off = 1; off < 16; off <<= 1) {
#pragma unroll
        for (int mi = 0; mi < 4; mi++)
#pragma unroll
            for (int r = 0; r < 4; r++) {
                float ob1 = __shfl_xor(b1[mi][r], off, 64);
                float ob2 = __shfl_xor(b2[mi][r], off, 64);
                int oi1 = __shfl_xor(i1[mi][r], off, 64);
                float lo = fminf(b1[mi][r], ob1);
                float hi = fmaxf(b1[mi][r], ob1);
                b2[mi][r] = fminf(fminf(b2[mi][r], ob2), hi);
                i1[mi][r] = (ob1 < b1[mi][r]) ? oi1 : i1[mi][r];
                b1[mi][r] = lo;
            }
    }

    if (c == 0) {
#pragma unroll
        for (int mi = 0; mi < 4; mi++)
#pragma unroll
            for (int r = 0; r < 4; r++) {
                int row = mi * 16 + quad * 4 + r;
                redb1[wid * 64 + row] = b1[mi][r];
                redb2[wid * 64 + row] = b2[mi][r];
                redi1[wid * 64 + row] = i1[mi][r];
            }
    }
    __syncthreads();

    if (t < 64) {
        float B1 = redb1[t], B2 = redb2[t];
        int I1 = redi1[t];
#pragma unroll
        for (int sl = 1; sl < NSLICE; sl++) {
            float ob1 = redb1[sl * 64 + t];
            float ob2 = redb2[sl * 64 + t];
            int oi1 = redi1[sl * 64 + t];
            float lo = fminf(B1, ob1);
            float hi = fmaxf(B1, ob1);
            B2 = fminf(fminf(B2, ob2), hi);
            I1 = (ob1 < B1) ? oi1 : I1;
            B1 = lo;
        }
        idx_out[rowbase + t] = I1;
        if (B2 - B1 < MARGIN_F) {
            rpart[rowbase + t] = ~0ull;          // init for rescue atomicMin
            int p = atomicAdd(rcount, 1);
            rlist[p] = rowbase + t;
        }
    }
}

// ---------------------------------------------------------------------------
// Kernel 3: exact fp32 rescue. Work item = (4-row group) x (512-code slice),
// grid-stride; emb chunk of 64 codes staged TRANSPOSED in LDS (coalesced
// global reads, stride-65 float2 -> conflict-free compute reads); z rows
// staged once (wave-uniform reads). Thread = (row r = t>>6, code c = t&63);
// result merged via packed u64 atomicMin (first-index tie-break exact).
// ---------------------------------------------------------------------------
#define RR 4        // rows per group
#define SC 512      // codes per slice
#define CH 64       // codes per staged chunk

__global__ void __launch_bounds__(256, 2)
rescue_kernel(const float* __restrict__ z,
              const float* __restrict__ emb,
              const float* __restrict__ enorm,
              const int* __restrict__ rcount,
              const int* __restrict__ rlist,
              unsigned long long* __restrict__ rpart) {
    __shared__ float2 ze[64 * RR];       // ze[d2*RR + r]
    __shared__ float2 es[64 * 65];       // es[d2*65 + code]
    __shared__ int ids[RR];

    const int t = threadIdx.x;
    const int cnt = *rcount;
    if (cnt == 0) return;
    const int ngrp = (cnt + RR - 1) / RR;
    const int nwork = ngrp * 8;

    const int r = t >> 6;                // 0..3 (== wave id)
    const int cl = t & 63;

    for (int g = blockIdx.x; g < nwork; g += gridDim.x) {
        const int gi = g >> 3;
        const int slice = g & 7;

        if (t < RR) {
            int j = gi * RR + t;
            ids[t] = rlist[j < cnt ? j : cnt - 1];
        }
        __syncthreads();                 // publish ids
        const int row = ids[r];
        ze[cl * RR + r] = ((const float2*)(z + (size_t)row * ND))[cl];  // coalesced

        unsigned long long bestp = ~0ull;
        const int kbase = slice * SC;

        for (int ch = 0; ch < SC / CH; ch++) {
            __syncthreads();             // es safe to overwrite (also publishes ze on ch==0)
#pragma unroll
            for (int q = 0; q < 16; q++) {
                int i = t + 256 * q;     // 0..4095
                int code = i >> 6;
                int d2 = i & 63;
                float2 v = ((const float2*)(emb + (size_t)(kbase + ch * CH + code) * ND))[d2];
                es[d2 * 65 + code] = v;
            }
            __syncthreads();

            int k = kbase + ch * CH + cl;
            float a0 = 0.f, a1 = 0.f, a2 = 0.f, a3 = 0.f;
#pragma unroll
            for (int d2 = 0; d2 < 64; d2 += 2) {
                float2 zv0 = ze[d2 * RR + r];            // wave-uniform
                float2 ev0 = es[d2 * 65 + cl];           // conflict-free
                float2 zv1 = ze[(d2 + 1) * RR + r];
                float2 ev1 = es[(d2 + 1) * 65 + cl];
                a0 = fmaf(zv0.x, ev0.x, a0);
                a1 = fmaf(zv0.y, ev0.y, a1);
                a2 = fmaf(zv1.x, ev1.x, a2);
                a3 = fmaf(zv1.y, ev1.y, a3);
            }
            float s = fmaf(-2.0f, (a0 + a1) + (a2 + a3), enorm[k]);
            unsigned long long p = pack_si(s, k);
            bestp = (p < bestp) ? p : bestp;
        }

        // wave-reduce min (all lanes in this wave share the same row)
#pragma unroll
        for (int off = 32; off > 0; off >>= 1) {
            unsigned long long o = __shfl_down(bestp, off, 64);
            bestp = (o < bestp) ? o : bestp;
        }
        if (cl == 0) atomicMin(&rpart[row], bestp);
        __syncthreads();                 // protect ids/ze before next g
    }
}

// ---------------------------------------------------------------------------
// Kernel 4: rescue finalize — unpack winning idx per rescue row.
// ---------------------------------------------------------------------------
__global__ void rescue_fin_kernel(const int* __restrict__ rcount,
                                  const int* __restrict__ rlist,
                                  const unsigned long long* __restrict__ rpart,
                                  int* __restrict__ idx_out) {
    const int cnt = *rcount;
    for (int i = blockIdx.x * blockDim.x + threadIdx.x; i < cnt;
         i += gridDim.x * blockDim.x) {
        int row = rlist[i];
        idx_out[row] = (int)(rpart[row] & 0xffffffffull);
    }
}

// ---------------------------------------------------------------------------
// Kernel 5: gather + loss partial + transposed write (unchanged).
// ---------------------------------------------------------------------------
__global__ void out_kernel(const float* __restrict__ z,
                           const float* __restrict__ emb,
                           const int* __restrict__ idx,
                           float* __restrict__ out,
                           float* __restrict__ losspart) {
    __shared__ float zq[64 * 129];
    __shared__ int ids[64];
    __shared__ float redl[4];

    const int bid = blockIdx.x;
    const int b = bid >> 6;
    const int h = bid & 63;
    const int rowbase = bid * 64;
    const int t = threadIdx.x;

    if (t < 64) ids[t] = idx[rowbase + t];
    __syncthreads();

    const int d = t & 127;
    const int w0 = t >> 7;
    float lsum = 0.f;
#pragma unroll
    for (int wq = 0; wq < 32; wq++) {
        int w = w0 + 2 * wq;
        float e = emb[(size_t)ids[w] * ND + d];
        float zv = z[((size_t)(rowbase + w)) * ND + d];
        float df = e - zv;
        lsum = fmaf(df, df, lsum);
        zq[w * 129 + d] = e;
    }
#pragma unroll
    for (int off = 32; off > 0; off >>= 1) lsum += __shfl_down(lsum, off, 64);
    if ((t & 63) == 0) redl[t >> 6] = lsum;
    __syncthreads();
    if (t == 0) losspart[bid] = redl[0] + redl[1] + redl[2] + redl[3];

    const int w = t & 63;
    const int dq = t >> 6;
#pragma unroll
    for (int dd0 = 0; dd0 < 32; dd0++) {
        int dd = dq + 4 * dd0;
        out[(((size_t)b * ND + dd) * NH + h) * NW + w] = zq[w * 129 + dd];
    }
}

// ---------------------------------------------------------------------------
// Kernel 6: final loss reduce
// ---------------------------------------------------------------------------
__global__ void loss_kernel(const float* __restrict__ losspart,
                            float* __restrict__ out) {
    __shared__ float redl[4];
    const int t = threadIdx.x;
    float s = 0.f;
#pragma unroll
    for (int i = 0; i < 4; i++) s += losspart[t + 256 * i];
#pragma unroll
    for (int off = 32; off > 0; off >>= 1) s += __shfl_down(s, off, 64);
    if ((t & 63) == 0) redl[t >> 6] = s;
    __syncthreads();
    if (t == 0) {
        float total = redl[0] + redl[1] + redl[2] + redl[3];
        out[OUT_ELEMS] = 1.25f * total / (float)OUT_ELEMS;
    }
}

// ---------------------------------------------------------------------------
extern "C" void kernel_launch(void* const* d_in, const int* in_sizes, int n_in,
                              void* d_out, int out_size, void* d_ws, size_t ws_size,
                              hipStream_t stream) {
    const float* z = (const float*)d_in[0];      // [16,64,64,128] fp32
    const float* emb = (const float*)d_in[1];    // [4096,128] fp32
    float* out = (float*)d_out;                  // 8388608 + 1 fp32

    char* ws = (char*)d_ws;
    int* ws_idx = (int*)ws;                                         // 256 KB
    float* ws_enorm = (float*)(ws + (256 << 10));                   // 16 KB
    float* ws_losspart = (float*)(ws + (272 << 10));                // 4 KB
    int* ws_rcount = (int*)(ws + (276 << 10));                      // 1 KB
    int* ws_rlist = (int*)(ws + (277 << 10));                       // 256 KB
    unsigned short* ws_eh = (unsigned short*)(ws + (533 << 10));    // 1 MB
    unsigned long long* ws_rpart = (unsigned long long*)(ws + (1557 << 10)); // 512 KB

    hipMemsetAsync(ws_rcount, 0, sizeof(int), stream);
    emb_prep_kernel<<<NK / 4, 256, 0, stream>>>(emb, ws_enorm, ws_eh);
    mfma_argmin_kernel<<<NROWS / 64, 256, 0, stream>>>(z, ws_eh, ws_enorm,
                                                       ws_idx, ws_rcount,
                                                       ws_rlist, ws_rpart);
    rescue_kernel<<<2048, 256, 0, stream>>>(z, emb, ws_enorm, ws_rcount,
                                            ws_rlist, ws_rpart);
    rescue_fin_kernel<<<64, 256, 0, stream>>>(ws_rcount, ws_rlist, ws_rpart,
                                              ws_idx);
    out_kernel<<<NB * NH, 256, 0, stream>>>(z, emb, ws_idx, out, ws_losspart);
    loss_kernel<<<1, 256, 0, stream>>>(ws_losspart, out);
}

// Round 7
// 411.537 us; speedup vs baseline: 1.4445x; 1.4445x over previous
//
#include <hip/hip_runtime.h>

// Problem constants
#define NB 16
#define NH 64
#define NW 64
#define ND 128
#define NK 4096
#define NROWS (NB * NH * NW)        // 65536
#define NSLICE 4
#define SLICE_K (NK / NSLICE)       // 1024
#define OUT_ELEMS (NB * ND * NH * NW)  // 8388608
// fp16 single-term fast path: score-gap error sigma ~= 0.013 (see journal);
// margin 0.10 ~= 8 sigma. Rescue handles everything below it exactly.
#define MARGIN_F 0.10f

typedef _Float16 f16x8 __attribute__((ext_vector_type(8)));
typedef float f32x4 __attribute__((ext_vector_type(4)));

__device__ __forceinline__ unsigned short f2h(float x) {
    _Float16 h = (_Float16)x;              // v_cvt_f16_f32, RNE
    return __builtin_bit_cast(unsigned short, h);
}
// Order-preserving (score,idx) packing: smaller score first, then smaller idx.
__device__ __forceinline__ unsigned long long pack_si(float s, int idx) {
    unsigned int u = __float_as_uint(s);
    unsigned int key = ((int)u < 0) ? ~u : (u | 0x80000000u);
    return ((unsigned long long)key << 32) | (unsigned int)idx;
}

// ---------------------------------------------------------------------------
// Kernel 1: emb prep — enorm (fp32 exact) + fp16 codebook e_h.
// ---------------------------------------------------------------------------
__global__ void emb_prep_kernel(const float* __restrict__ emb,
                                float* __restrict__ enorm,
                                unsigned short* __restrict__ e_h) {
    int wave = (blockIdx.x * blockDim.x + threadIdx.x) >> 6;
    int lane = threadIdx.x & 63;
    if (wave >= NK) return;
    const float* e = emb + (size_t)wave * ND;
    float a = e[lane];
    float b = e[lane + 64];
    e_h[(size_t)wave * ND + lane] = f2h(a);
    e_h[(size_t)wave * ND + lane + 64] = f2h(b);
    float s = a * a + b * b;
#pragma unroll
    for (int off = 32; off > 0; off >>= 1) s += __shfl_down(s, off, 64);
    if (lane == 0) enorm[wave] = s;
}

// ---------------------------------------------------------------------------
// Kernel 2: MFMA argmin. fp16 single-MFMA fast path, waves_per_eu(2,2).
// Occupancy ledger: natural demand ~184 unified regs/wave (120 arch + 64
// acc). (4,4) budget 128 -> spill (FETCH 802MB, 358us). (3,4) budget 170 ->
// still spills (84 arch, FETCH 364MB, 409us) AND occupancy stays 2 w/SIMD.
// => 2 waves/SIMD is forced by register demand; (2,2) is the no-spill point.
// R13 change: hoist all 16 B-frag loads to step top (bv[16] window) so the
// 4 L2 latency exposures per step collapse to 1. ~212 regs < 256 budget.
// ---------------------------------------------------------------------------
#define ZST 136   // LDS row stride in ushort

__global__ void
__attribute__((amdgpu_flat_work_group_size(256, 256), amdgpu_waves_per_eu(2, 2)))
mfma_argmin_kernel(const float* __restrict__ z,
                   const unsigned short* __restrict__ e_h,
                   const float* __restrict__ enorm,
                   int* __restrict__ idx_out,
                   int* __restrict__ rcount,
                   int* __restrict__ rlist,
                   unsigned long long* __restrict__ rpart) {
    __shared__ unsigned short zh[64 * ZST];
    __shared__ float redb1[NSLICE * 64];
    __shared__ float redb2[NSLICE * 64];
    __shared__ int redi1[NSLICE * 64];

    const int bid = blockIdx.x;
    const int rowbase = bid * 64;
    const int t = threadIdx.x;

    const float4* zg = (const float4*)(z + (size_t)rowbase * ND);
#pragma unroll
    for (int q = 0; q < 8; q++) {
        int i = t + 256 * q;               // 0..2047
        float4 v = zg[i];
        int r = i >> 5;
        int c4 = (i & 31) << 2;
        ushort4 hv = make_ushort4(f2h(v.x), f2h(v.y), f2h(v.z), f2h(v.w));
        *(ushort4*)&zh[r * ZST + c4] = hv;
    }
    __syncthreads();

    const int lane = t & 63;
    const int wid = __builtin_amdgcn_readfirstlane(t >> 6);
    const int quad = lane >> 4;
    const int c = lane & 15;
    const int n0 = wid * SLICE_K;

    float b1[4][4], b2[4][4];
    int i1[4][4];
#pragma unroll
    for (int mi = 0; mi < 4; mi++)
#pragma unroll
        for (int r = 0; r < 4; r++) { b1[mi][r] = 3.4e38f; b2[mi][r] = 3.4e38f; i1[mi][r] = 0; }

    const int aoff = c * ZST + quad * 8;
    const unsigned short* pbh = e_h + c * ND + quad * 8;

    for (int nb = n0; nb < n0 + SLICE_K; nb += 64) {
        // Hoisted B window: issue all 16 fragment loads back-to-back so they
        // pipeline through L2 — one latency wait per step, not one per kk.
        f16x8 bv[16];
#pragma unroll
        for (int u = 0; u < 16; u++) {
            int ni = u >> 2;
            int kk = u & 3;
            bv[u] = *(const f16x8*)(pbh + (size_t)(nb + ni * 16) * ND + kk * 32);
        }

        f32x4 acc[4][4];
#pragma unroll
        for (int mi = 0; mi < 4; mi++)
#pragma unroll
            for (int ni = 0; ni < 4; ni++) acc[mi][ni] = (f32x4){0.f, 0.f, 0.f, 0.f};

#pragma unroll
        for (int kk = 0; kk < 4; kk++) {
            f16x8 ah[4];
#pragma unroll
            for (int mi = 0; mi < 4; mi++)
                ah[mi] = *(const f16x8*)&zh[aoff + mi * (16 * ZST) + kk * 32];
#pragma unroll
            for (int ni = 0; ni < 4; ni++) {
#pragma unroll
                for (int mi = 0; mi < 4; mi++)
                    acc[mi][ni] = __builtin_amdgcn_mfma_f32_16x16x32_f16(ah[mi], bv[ni * 4 + kk], acc[mi][ni], 0, 0, 0);
            }
        }

#pragma unroll
        for (int ni = 0; ni < 4; ni++) {
            int n = nb + ni * 16 + c;
            float en = enorm[n];
#pragma unroll
            for (int mi = 0; mi < 4; mi++)
#pragma unroll
                for (int r = 0; r < 4; r++) {
                    float s = fmaf(-2.0f, acc[mi][ni][r], en);
                    if (s < b1[mi][r]) { b2[mi][r] = b1[mi][r]; b1[mi][r] = s; i1[mi][r] = n; }
                    else if (s < b2[mi][r]) b2[mi][r] = s;
                }
        }
    }

#pragma unroll
    for (int off = 1; off < 16; off <<= 1) {
#pragma unroll
        for (int mi = 0; mi < 4; mi++)
#pragma unroll
            for (int r = 0; r < 4; r++) {
                float ob1 = __shfl_xor(b1[mi][r], off, 64);
                float ob2 = __shfl_xor(b2[mi][r], off, 64);
                int oi1 = __shfl_xor(i1[mi][r], off, 64);
                float lo = fminf(b1[mi][r], ob1);
                float hi = fmaxf(b1[mi][r], ob1);
                b2[mi][r] = fminf(fminf(b2[mi][r], ob2), hi);
                i1[mi][r] = (ob1 < b1[mi][r]) ? oi1 : i1[mi][r];
                b1[mi][r] = lo;
            }
    }

    if (c == 0) {
#pragma unroll
        for (int mi = 0; mi < 4; mi++)
#pragma unroll
            for (int r = 0; r < 4; r++) {
                int row = mi * 16 + quad * 4 + r;
                redb1[wid * 64 + row] = b1[mi][r];
                redb2[wid * 64 + row] = b2[mi][r];
                redi1[wid * 64 + row] = i1[mi][r];
            }
    }
    __syncthreads();

    if (t < 64) {
        float B1 = redb1[t], B2 = redb2[t];
        int I1 = redi1[t];
#pragma unroll
        for (int sl = 1; sl < NSLICE; sl++) {
            float ob1 = redb1[sl * 64 + t];
            float ob2 = redb2[sl * 64 + t];
            int oi1 = redi1[sl * 64 + t];
            float lo = fminf(B1, ob1);
            float hi = fmaxf(B1, ob1);
            B2 = fminf(fminf(B2, ob2), hi);
            I1 = (ob1 < B1) ? oi1 : I1;
            B1 = lo;
        }
        idx_out[rowbase + t] = I1;
        if (B2 - B1 < MARGIN_F) {
            rpart[rowbase + t] = ~0ull;          // init for rescue atomicMin
            int p = atomicAdd(rcount, 1);
            rlist[p] = rowbase + t;
        }
    }
}

// ---------------------------------------------------------------------------
// Kernel 3: exact fp32 rescue. Work item = (4-row group) x (512-code slice),
// grid-stride; emb chunk of 64 codes staged TRANSPOSED in LDS (coalesced
// global reads, stride-65 float2 -> conflict-free compute reads); z rows
// staged once (wave-uniform reads). Thread = (row r = t>>6, code c = t&63);
// result merged via packed u64 atomicMin (first-index tie-break exact).
// ---------------------------------------------------------------------------
#define RR 4        // rows per group
#define SC 512      // codes per slice
#define CH 64       // codes per staged chunk

__global__ void __launch_bounds__(256, 2)
rescue_kernel(const float* __restrict__ z,
              const float* __restrict__ emb,
              const float* __restrict__ enorm,
              const int* __restrict__ rcount,
              const int* __restrict__ rlist,
              unsigned long long* __restrict__ rpart) {
    __shared__ float2 ze[64 * RR];       // ze[d2*RR + r]
    __shared__ float2 es[64 * 65];       // es[d2*65 + code]
    __shared__ int ids[RR];

    const int t = threadIdx.x;
    const int cnt = *rcount;
    if (cnt == 0) return;
    const int ngrp = (cnt + RR - 1) / RR;
    const int nwork = ngrp * 8;

    const int r = t >> 6;                // 0..3 (== wave id)
    const int cl = t & 63;

    for (int g = blockIdx.x; g < nwork; g += gridDim.x) {
        const int gi = g >> 3;
        const int slice = g & 7;

        if (t < RR) {
            int j = gi * RR + t;
            ids[t] = rlist[j < cnt ? j : cnt - 1];
        }
        __syncthreads();                 // publish ids
        const int row = ids[r];
        ze[cl * RR + r] = ((const float2*)(z + (size_t)row * ND))[cl];  // coalesced

        unsigned long long bestp = ~0ull;
        const int kbase = slice * SC;

        for (int ch = 0; ch < SC / CH; ch++) {
            __syncthreads();             // es safe to overwrite (also publishes ze on ch==0)
#pragma unroll
            for (int q = 0; q < 16; q++) {
                int i = t + 256 * q;     // 0..4095
                int code = i >> 6;
                int d2 = i & 63;
                float2 v = ((const float2*)(emb + (size_t)(kbase + ch * CH + code) * ND))[d2];
                es[d2 * 65 + code] = v;
            }
            __syncthreads();

            int k = kbase + ch * CH + cl;
            float a0 = 0.f, a1 = 0.f, a2 = 0.f, a3 = 0.f;
#pragma unroll
            for (int d2 = 0; d2 < 64; d2 += 2) {
                float2 zv0 = ze[d2 * RR + r];            // wave-uniform
                float2 ev0 = es[d2 * 65 + cl];           // conflict-free
                float2 zv1 = ze[(d2 + 1) * RR + r];
                float2 ev1 = es[(d2 + 1) * 65 + cl];
                a0 = fmaf(zv0.x, ev0.x, a0);
                a1 = fmaf(zv0.y, ev0.y, a1);
                a2 = fmaf(zv1.x, ev1.x, a2);
                a3 = fmaf(zv1.y, ev1.y, a3);
            }
            float s = fmaf(-2.0f, (a0 + a1) + (a2 + a3), enorm[k]);
            unsigned long long p = pack_si(s, k);
            bestp = (p < bestp) ? p : bestp;
        }

        // wave-reduce min (all lanes in this wave share the same row)
#pragma unroll
        for (int off = 32; off > 0; off >>= 1) {
            unsigned long long o = __shfl_down(bestp, off, 64);
            bestp = (o < bestp) ? o : bestp;
        }
        if (cl == 0) atomicMin(&rpart[row], bestp);
        __syncthreads();                 // protect ids/ze before next g
    }
}

// ---------------------------------------------------------------------------
// Kernel 4: rescue finalize — unpack winning idx per rescue row.
// ---------------------------------------------------------------------------
__global__ void rescue_fin_kernel(const int* __restrict__ rcount,
                                  const int* __restrict__ rlist,
                                  const unsigned long long* __restrict__ rpart,
                                  int* __restrict__ idx_out) {
    const int cnt = *rcount;
    for (int i = blockIdx.x * blockDim.x + threadIdx.x; i < cnt;
         i += gridDim.x * blockDim.x) {
        int row = rlist[i];
        idx_out[row] = (int)(rpart[row] & 0xffffffffull);
    }
}

// ---------------------------------------------------------------------------
// Kernel 5: gather + loss partial + transposed write (unchanged).
// ---------------------------------------------------------------------------
__global__ void out_kernel(const float* __restrict__ z,
                           const float* __restrict__ emb,
                           const int* __restrict__ idx,
                           float* __restrict__ out,
                           float* __restrict__ losspart) {
    __shared__ float zq[64 * 129];
    __shared__ int ids[64];
    __shared__ float redl[4];

    const int bid = blockIdx.x;
    const int b = bid >> 6;
    const int h = bid & 63;
    const int rowbase = bid * 64;
    const int t = threadIdx.x;

    if (t < 64) ids[t] = idx[rowbase + t];
    __syncthreads();

    const int d = t & 127;
    const int w0 = t >> 7;
    float lsum = 0.f;
#pragma unroll
    for (int wq = 0; wq < 32; wq++) {
        int w = w0 + 2 * wq;
        float e = emb[(size_t)ids[w] * ND + d];
        float zv = z[((size_t)(rowbase + w)) * ND + d];
        float df = e - zv;
        lsum = fmaf(df, df, lsum);
        zq[w * 129 + d] = e;
    }
#pragma unroll
    for (int off = 32; off > 0; off >>= 1) lsum += __shfl_down(lsum, off, 64);
    if ((t & 63) == 0) redl[t >> 6] = lsum;
    __syncthreads();
    if (t == 0) losspart[bid] = redl[0] + redl[1] + redl[2] + redl[3];

    const int w = t & 63;
    const int dq = t >> 6;
#pragma unroll
    for (int dd0 = 0; dd0 < 32; dd0++) {
        int dd = dq + 4 * dd0;
        out[(((size_t)b * ND + dd) * NH + h) * NW + w] = zq[w * 129 + dd];
    }
}

// ---------------------------------------------------------------------------
// Kernel 6: final loss reduce
// ---------------------------------------------------------------------------
__global__ void loss_kernel(const float* __restrict__ losspart,
                            float* __restrict__ out) {
    __shared__ float redl[4];
    const int t = threadIdx.x;
    float s = 0.f;
#pragma unroll
    for (int i = 0; i < 4; i++) s += losspart[t + 256 * i];
#pragma unroll
    for (int off = 32; off > 0; off >>= 1) s += __shfl_down(s, off, 64);
    if ((t & 63) == 0) redl[t >> 6] = s;
    __syncthreads();
    if (t == 0) {
        float total = redl[0] + redl[1] + redl[2] + redl[3];
        out[OUT_ELEMS] = 1.25f * total / (float)OUT_ELEMS;
    }
}

// ---------------------------------------------------------------------------
extern "C" void kernel_launch(void* const* d_in, const int* in_sizes, int n_in,
                              void* d_out, int out_size, void* d_ws, size_t ws_size,
                              hipStream_t stream) {
    const float* z = (const float*)d_in[0];      // [16,64,64,128] fp32
    const float* emb = (const float*)d_in[1];    // [4096,128] fp32
    float* out = (float*)d_out;                  // 8388608 + 1 fp32

    char* ws = (char*)d_ws;
    int* ws_idx = (int*)ws;                                         // 256 KB
    float* ws_enorm = (float*)(ws + (256 << 10));                   // 16 KB
    float* ws_losspart = (float*)(ws + (272 << 10));                // 4 KB
    int* ws_rcount = (int*)(ws + (276 << 10));                      // 1 KB
    int* ws_rlist = (int*)(ws + (277 << 10));                       // 256 KB
    unsigned short* ws_eh = (unsigned short*)(ws + (533 << 10));    // 1 MB
    unsigned long long* ws_rpart = (unsigned long long*)(ws + (1557 << 10)); // 512 KB

    hipMemsetAsync(ws_rcount, 0, sizeof(int), stream);
    emb_prep_kernel<<<NK / 4, 256, 0, stream>>>(emb, ws_enorm, ws_eh);
    mfma_argmin_kernel<<<NROWS / 64, 256, 0, stream>>>(z, ws_eh, ws_enorm,
                                                       ws_idx, ws_rcount,
                                                       ws_rlist, ws_rpart);
    rescue_kernel<<<2048, 256, 0, stream>>>(z, emb, ws_enorm, ws_rcount,
                                            ws_rlist, ws_rpart);
    rescue_fin_kernel<<<64, 256, 0, stream>>>(ws_rcount, ws_rlist, ws_rpart,
                                              ws_idx);
    out_kernel<<<NB * NH, 256, 0, stream>>>(z, emb, ws_idx, out, ws_losspart);
    loss_kernel<<<1, 256, 0, stream>>>(ws_losspart, out);
}

// Round 8
// 405.160 us; speedup vs baseline: 1.4672x; 1.0157x over previous
//
#include <hip/hip_runtime.h>

// Problem constants
#define NB 16
#define NH 64
#define NW 64
#define ND 128
#define NK 4096
#define NROWS (NB * NH * NW)        // 65536
#define OUT_ELEMS (NB * ND * NH * NW)  // 8388608
// fp16 single-term fast path: score-gap error sigma ~= 0.013; margin 0.10
// ~= 8 sigma. Exact-fp32 rescue handles everything below the margin.
#define MARGIN_F 0.10f

typedef _Float16 f16x8 __attribute__((ext_vector_type(8)));
typedef float f32x4 __attribute__((ext_vector_type(4)));

__device__ __forceinline__ unsigned short f2h(float x) {
    _Float16 h = (_Float16)x;              // v_cvt_f16_f32, RNE
    return __builtin_bit_cast(unsigned short, h);
}
// Order-preserving (score,idx) packing: smaller score first, then smaller idx.
__device__ __forceinline__ unsigned long long pack_si(float s, int idx) {
    unsigned int u = __float_as_uint(s);
    unsigned int key = ((int)u < 0) ? ~u : (u | 0x80000000u);
    return ((unsigned long long)key << 32) | (unsigned int)idx;
}

// ---------------------------------------------------------------------------
// Kernel 1: emb prep — enorm (fp32 exact) + fp16 codebook e_h stored in a
// SWIZZLED layout: ushort index = code*128 + (dim ^ ((code&7)<<3)).
// global_load_lds copies tiles verbatim (it cannot scatter), so the LDS
// bank-conflict swizzle must be pre-baked into the global layout (m173
// pattern: swizzle both sides or neither). Bijective within each code row.
// ---------------------------------------------------------------------------
__global__ void emb_prep_kernel(const float* __restrict__ emb,
                                float* __restrict__ enorm,
                                unsigned short* __restrict__ e_h) {
    int wave = (blockIdx.x * blockDim.x + threadIdx.x) >> 6;
    int lane = threadIdx.x & 63;
    if (wave >= NK) return;
    const float* e = emb + (size_t)wave * ND;
    float a = e[lane];
    float b = e[lane + 64];
    const int m = (wave & 7) << 3;
    e_h[(size_t)wave * ND + (lane ^ m)] = f2h(a);
    e_h[(size_t)wave * ND + ((lane + 64) ^ m)] = f2h(b);
    float s = a * a + b * b;
#pragma unroll
    for (int off = 32; off > 0; off >>= 1) s += __shfl_down(s, off, 64);
    if (lane == 0) enorm[wave] = s;
}

// ---------------------------------------------------------------------------
// Kernel 2: MFMA argmin, restructured (R8).
// History: (2,2)-pinned + per-wave global B loads = 225us, 56% stall (no
// pipe >30%) — L2 latency per step, compiler won't pipeline (R7 hoist null).
// New: per step the block stages one shared 64-code tile (16 KB fp16) into
// LDS via global_load_lds, double-buffered (issue STAGE(next) -> compute ->
// barrier). Waves = (row-half, code-half): mi=2 x ni=2 x kk=4 = 16 MFMA per
// wave-step, B reads from swizzled LDS (conflict-free-ish per attn m214
// pattern). Regs ~110 (acc 16 + top2 24), LDS 51.7 KB -> 3 blocks/CU.
// ---------------------------------------------------------------------------
#define ZST 136   // zh row stride in ushort (272 B, conflict-measured OK)

__global__ void
__attribute__((amdgpu_flat_work_group_size(256, 256)))
mfma_argmin_kernel(const float* __restrict__ z,
                   const unsigned short* __restrict__ e_h,
                   const float* __restrict__ enorm,
                   int* __restrict__ idx_out,
                   int* __restrict__ rcount,
                   int* __restrict__ rlist,
                   unsigned long long* __restrict__ rpart) {
    __shared__ alignas(16) unsigned short zh[64 * ZST];        // 17408 B
    __shared__ alignas(16) unsigned short btile[2][64 * ND];   // 32768 B
    __shared__ float redb1[2 * 64];
    __shared__ float redb2[2 * 64];
    __shared__ int   redi1[2 * 64];

    const int bid = blockIdx.x;
    const int rowbase = bid * 64;
    const int t = threadIdx.x;
    const int lane = t & 63;
    const int wid = __builtin_amdgcn_readfirstlane(t >> 6);

    // ---- stage z rows (fp32 -> fp16) into zh ----
    const float4* zg = (const float4*)(z + (size_t)rowbase * ND);
#pragma unroll
    for (int q = 0; q < 8; q++) {
        int i = t + 256 * q;               // 0..2047
        float4 v = zg[i];
        int r = i >> 5;
        int c4 = (i & 31) << 2;
        ushort4 hv = make_ushort4(f2h(v.x), f2h(v.y), f2h(v.z), f2h(v.w));
        *(ushort4*)&zh[r * ZST + c4] = hv;
    }

    // ---- prologue: stage code-tile 0 into btile[0] (16 segments of 1 KB;
    //      wave w stages segments w*4..w*4+3; LDS dest = base + lane*16) ----
    {
        const unsigned short* gt = e_h;
#pragma unroll
        for (int j = 0; j < 4; j++) {
            int seg = (wid << 2) + j;
            __builtin_amdgcn_global_load_lds(
                (const unsigned int*)(gt + seg * 512 + lane * 8),
                (unsigned int*)&btile[0][seg * 512], 16, 0, 0);
        }
    }
    __syncthreads();   // drains zh ds_writes + tile-0 vmcnt

    const int quad = lane >> 4;
    const int c = lane & 15;
    const int rh = wid >> 1;               // row half (rows rh*32..rh*32+31)
    const int ch = wid & 1;                // code half within each tile
    const int arow0 = (rh * 32 + c) * ZST + quad * 8;
    const int bswz = (c & 7) << 3;         // read-side swizzle (matches prep)
    const int bbase0 = (ch * 32 + c) * ND;

    float b1[2][4], b2[2][4];
    int i1[2][4];
#pragma unroll
    for (int mi = 0; mi < 2; mi++)
#pragma unroll
        for (int r = 0; r < 4; r++) { b1[mi][r] = 3.4e38f; b2[mi][r] = 3.4e38f; i1[mi][r] = 0; }

    for (int ts = 0; ts < NK / 64; ts++) {
        const int cur = ts & 1;
        // issue next tile's stage FIRST — latency hides under this step's
        // compute; the pre-barrier drain at loop end completes it.
        if (ts < NK / 64 - 1) {
            const unsigned short* gt = e_h + (size_t)(ts + 1) * (64 * ND);
#pragma unroll
            for (int j = 0; j < 4; j++) {
                int seg = (wid << 2) + j;
                __builtin_amdgcn_global_load_lds(
                    (const unsigned int*)(gt + seg * 512 + lane * 8),
                    (unsigned int*)&btile[cur ^ 1][seg * 512], 16, 0, 0);
            }
        }

        float en0 = enorm[ts * 64 + ch * 32 + c];
        float en1 = enorm[ts * 64 + ch * 32 + 16 + c];

        f32x4 acc[2][2];
#pragma unroll
        for (int mi = 0; mi < 2; mi++)
#pragma unroll
            for (int ni = 0; ni < 2; ni++) acc[mi][ni] = (f32x4){0.f, 0.f, 0.f, 0.f};

#pragma unroll
        for (int kk = 0; kk < 4; kk++) {
            f16x8 ah0 = *(const f16x8*)&zh[arow0 + kk * 32];
            f16x8 ah1 = *(const f16x8*)&zh[arow0 + 16 * ZST + kk * 32];
            const int doff = (quad * 8 + kk * 32) ^ bswz;
            f16x8 bv0 = *(const f16x8*)&btile[cur][bbase0 + doff];
            f16x8 bv1 = *(const f16x8*)&btile[cur][bbase0 + 16 * ND + doff];
            acc[0][0] = __builtin_amdgcn_mfma_f32_16x16x32_f16(ah0, bv0, acc[0][0], 0, 0, 0);
            acc[0][1] = __builtin_amdgcn_mfma_f32_16x16x32_f16(ah0, bv1, acc[0][1], 0, 0, 0);
            acc[1][0] = __builtin_amdgcn_mfma_f32_16x16x32_f16(ah1, bv0, acc[1][0], 0, 0, 0);
            acc[1][1] = __builtin_amdgcn_mfma_f32_16x16x32_f16(ah1, bv1, acc[1][1], 0, 0, 0);
        }

#pragma unroll
        for (int ni = 0; ni < 2; ni++) {
            const int n = ts * 64 + ch * 32 + ni * 16 + c;
            const float en = ni ? en1 : en0;
#pragma unroll
            for (int mi = 0; mi < 2; mi++)
#pragma unroll
                for (int r = 0; r < 4; r++) {
                    float s = fmaf(-2.0f, acc[mi][ni][r], en);
                    if (s < b1[mi][r]) { b2[mi][r] = b1[mi][r]; b1[mi][r] = s; i1[mi][r] = n; }
                    else if (s < b2[mi][r]) b2[mi][r] = s;
                }
        }

        // one barrier per step: (a) next tile staged for everyone,
        // (b) everyone done reading cur before it is overwritten next step.
        __syncthreads();
    }

    // ---- reduce over the 16 c-lanes (codes) within each wave ----
#pragma unroll
    for (int off = 1; off < 16; off <<= 1) {
#pragma unroll
        for (int mi = 0; mi < 2; mi++)
#pragma unroll
            for (int r = 0; r < 4; r++) {
                float ob1 = __shfl_xor(b1[mi][r], off, 64);
                float ob2 = __shfl_xor(b2[mi][r], off, 64);
                int oi1 = __shfl_xor(i1[mi][r], off, 64);
                float lo = fminf(b1[mi][r], ob1);
                float hi = fmaxf(b1[mi][r], ob1);
                b2[mi][r] = fminf(fminf(b2[mi][r], ob2), hi);
                i1[mi][r] = (ob1 < b1[mi][r]) ? oi1 : i1[mi][r];
                b1[mi][r] = lo;
            }
    }

    // ---- 2-way merge across code-halves (same rows held by ch=0 and ch=1) ----
    if (c == 0) {
#pragma unroll
        for (int mi = 0; mi < 2; mi++)
#pragma unroll
            for (int r = 0; r < 4; r++) {
                int rowl = rh * 32 + mi * 16 + quad * 4 + r;
                redb1[ch * 64 + rowl] = b1[mi][r];
                redb2[ch * 64 + rowl] = b2[mi][r];
                redi1[ch * 64 + rowl] = i1[mi][r];
            }
    }
    __syncthreads();

    if (t < 64) {
        float B1 = redb1[t], B2 = redb2[t];
        int I1 = redi1[t];
        float ob1 = redb1[64 + t];
        float ob2 = redb2[64 + t];
        int oi1 = redi1[64 + t];
        float lo = fminf(B1, ob1);
        float hi = fmaxf(B1, ob1);
        B2 = fminf(fminf(B2, ob2), hi);
        I1 = (ob1 < B1) ? oi1 : I1;
        B1 = lo;
        idx_out[rowbase + t] = I1;
        if (B2 - B1 < MARGIN_F) {
            rpart[rowbase + t] = ~0ull;          // init for rescue atomicMin
            int p = atomicAdd(rcount, 1);
            rlist[p] = rowbase + t;
        }
    }
}

// ---------------------------------------------------------------------------
// Kernel 3: exact fp32 rescue (unchanged; reads fp32 emb, unswizzled).
// ---------------------------------------------------------------------------
#define RR 4        // rows per group
#define SC 512      // codes per slice
#define CH 64       // codes per staged chunk

__global__ void __launch_bounds__(256, 2)
rescue_kernel(const float* __restrict__ z,
              const float* __restrict__ emb,
              const float* __restrict__ enorm,
              const int* __restrict__ rcount,
              const int* __restrict__ rlist,
              unsigned long long* __restrict__ rpart) {
    __shared__ float2 ze[64 * RR];       // ze[d2*RR + r]
    __shared__ float2 es[64 * 65];       // es[d2*65 + code]
    __shared__ int ids[RR];

    const int t = threadIdx.x;
    const int cnt = *rcount;
    if (cnt == 0) return;
    const int ngrp = (cnt + RR - 1) / RR;
    const int nwork = ngrp * 8;

    const int r = t >> 6;                // 0..3 (== wave id)
    const int cl = t & 63;

    for (int g = blockIdx.x; g < nwork; g += gridDim.x) {
        const int gi = g >> 3;
        const int slice = g & 7;

        if (t < RR) {
            int j = gi * RR + t;
            ids[t] = rlist[j < cnt ? j : cnt - 1];
        }
        __syncthreads();                 // publish ids
        const int row = ids[r];
        ze[cl * RR + r] = ((const float2*)(z + (size_t)row * ND))[cl];  // coalesced

        unsigned long long bestp = ~0ull;
        const int kbase = slice * SC;

        for (int ch2 = 0; ch2 < SC / CH; ch2++) {
            __syncthreads();             // es safe to overwrite (also publishes ze on ch2==0)
#pragma unroll
            for (int q = 0; q < 16; q++) {
                int i = t + 256 * q;     // 0..4095
                int code = i >> 6;
                int d2 = i & 63;
                float2 v = ((const float2*)(emb + (size_t)(kbase + ch2 * CH + code) * ND))[d2];
                es[d2 * 65 + code] = v;
            }
            __syncthreads();

            int k = kbase + ch2 * CH + cl;
            float a0 = 0.f, a1 = 0.f, a2 = 0.f, a3 = 0.f;
#pragma unroll
            for (int d2 = 0; d2 < 64; d2 += 2) {
                float2 zv0 = ze[d2 * RR + r];            // wave-uniform
                float2 ev0 = es[d2 * 65 + cl];           // conflict-free
                float2 zv1 = ze[(d2 + 1) * RR + r];
                float2 ev1 = es[(d2 + 1) * 65 + cl];
                a0 = fmaf(zv0.x, ev0.x, a0);
                a1 = fmaf(zv0.y, ev0.y, a1);
                a2 = fmaf(zv1.x, ev1.x, a2);
                a3 = fmaf(zv1.y, ev1.y, a3);
            }
            float s = fmaf(-2.0f, (a0 + a1) + (a2 + a3), enorm[k]);
            unsigned long long p = pack_si(s, k);
            bestp = (p < bestp) ? p : bestp;
        }

        // wave-reduce min (all lanes in this wave share the same row)
#pragma unroll
        for (int off = 32; off > 0; off >>= 1) {
            unsigned long long o = __shfl_down(bestp, off, 64);
            bestp = (o < bestp) ? o : bestp;
        }
        if (cl == 0) atomicMin(&rpart[row], bestp);
        __syncthreads();                 // protect ids/ze before next g
    }
}

// ---------------------------------------------------------------------------
// Kernel 4: rescue finalize — unpack winning idx per rescue row.
// ---------------------------------------------------------------------------
__global__ void rescue_fin_kernel(const int* __restrict__ rcount,
                                  const int* __restrict__ rlist,
                                  const unsigned long long* __restrict__ rpart,
                                  int* __restrict__ idx_out) {
    const int cnt = *rcount;
    for (int i = blockIdx.x * blockDim.x + threadIdx.x; i < cnt;
         i += gridDim.x * blockDim.x) {
        int row = rlist[i];
        idx_out[row] = (int)(rpart[row] & 0xffffffffull);
    }
}

// ---------------------------------------------------------------------------
// Kernel 5: gather + loss partial + transposed write (unchanged).
// ---------------------------------------------------------------------------
__global__ void out_kernel(const float* __restrict__ z,
                           const float* __restrict__ emb,
                           const int* __restrict__ idx,
                           float* __restrict__ out,
                           float* __restrict__ losspart) {
    __shared__ float zq[64 * 129];
    __shared__ int ids[64];
    __shared__ float redl[4];

    const int bid = blockIdx.x;
    const int b = bid >> 6;
    const int h = bid & 63;
    const int rowbase = bid * 64;
    const int t = threadIdx.x;

    if (t < 64) ids[t] = idx[rowbase + t];
    __syncthreads();

    const int d = t & 127;
    const int w0 = t >> 7;
    float lsum = 0.f;
#pragma unroll
    for (int wq = 0; wq < 32; wq++) {
        int w = w0 + 2 * wq;
        float e = emb[(size_t)ids[w] * ND + d];
        float zv = z[((size_t)(rowbase + w)) * ND + d];
        float df = e - zv;
        lsum = fmaf(df, df, lsum);
        zq[w * 129 + d] = e;
    }
#pragma unroll
    for (int off = 32; off > 0; off >>= 1) lsum += __shfl_down(lsum, off, 64);
    if ((t & 63) == 0) redl[t >> 6] = lsum;
    __syncthreads();
    if (t == 0) losspart[bid] = redl[0] + redl[1] + redl[2] + redl[3];

    const int w = t & 63;
    const int dq = t >> 6;
#pragma unroll
    for (int dd0 = 0; dd0 < 32; dd0++) {
        int dd = dq + 4 * dd0;
        out[(((size_t)b * ND + dd) * NH + h) * NW + w] = zq[w * 129 + dd];
    }
}

// ---------------------------------------------------------------------------
// Kernel 6: final loss reduce
// ---------------------------------------------------------------------------
__global__ void loss_kernel(const float* __restrict__ losspart,
                            float* __restrict__ out) {
    __shared__ float redl[4];
    const int t = threadIdx.x;
    float s = 0.f;
#pragma unroll
    for (int i = 0; i < 4; i++) s += losspart[t + 256 * i];
#pragma unroll
    for (int off = 32; off > 0; off >>= 1) s += __shfl_down(s, off, 64);
    if ((t & 63) == 0) redl[t >> 6] = s;
    __syncthreads();
    if (t == 0) {
        float total = redl[0] + redl[1] + redl[2] + redl[3];
        out[OUT_ELEMS] = 1.25f * total / (float)OUT_ELEMS;
    }
}

// ---------------------------------------------------------------------------
extern "C" void kernel_launch(void* const* d_in, const int* in_sizes, int n_in,
                              void* d_out, int out_size, void* d_ws, size_t ws_size,
                              hipStream_t stream) {
    const float* z = (const float*)d_in[0];      // [16,64,64,128] fp32
    const float* emb = (const float*)d_in[1];    // [4096,128] fp32
    float* out = (float*)d_out;                  // 8388608 + 1 fp32

    char* ws = (char*)d_ws;
    int* ws_idx = (int*)ws;                                         // 256 KB
    float* ws_enorm = (float*)(ws + (256 << 10));                   // 16 KB
    float* ws_losspart = (float*)(ws + (272 << 10));                // 4 KB
    int* ws_rcount = (int*)(ws + (276 << 10));                      // 1 KB
    int* ws_rlist = (int*)(ws + (277 << 10));                       // 256 KB
    unsigned short* ws_eh = (unsigned short*)(ws + (533 << 10));    // 1 MB
    unsigned long long* ws_rpart = (unsigned long long*)(ws + (1557 << 10)); // 512 KB

    hipMemsetAsync(ws_rcount, 0, sizeof(int), stream);
    emb_prep_kernel<<<NK / 4, 256, 0, stream>>>(emb, ws_enorm, ws_eh);
    mfma_argmin_kernel<<<NROWS / 64, 256, 0, stream>>>(z, ws_eh, ws_enorm,
                                                       ws_idx, ws_rcount,
                                                       ws_rlist, ws_rpart);
    rescue_kernel<<<2048, 256, 0, stream>>>(z, emb, ws_enorm, ws_rcount,
                                            ws_rlist, ws_rpart);
    rescue_fin_kernel<<<64, 256, 0, stream>>>(ws_rcount, ws_rlist, ws_rpart,
                                              ws_idx);
    out_kernel<<<NB * NH, 256, 0, stream>>>(z, emb, ws_idx, out, ws_losspart);
    loss_kernel<<<1, 256, 0, stream>>>(ws_losspart, out);
}

// Round 9
// 387.789 us; speedup vs baseline: 1.5330x; 1.0448x over previous
//
#include <hip/hip_runtime.h>

// Problem constants
#define NB 16
#define NH 64
#define NW 64
#define ND 128
#define NK 4096
#define NROWS (NB * NH * NW)        // 65536
#define OUT_ELEMS (NB * ND * NH * NW)  // 8388608
// fp16 single-term fast path: score-gap error sigma ~= 0.013; margin 0.10
// ~= 8 sigma. Exact-fp32 rescue handles everything below the margin.
#define MARGIN_F 0.10f

typedef _Float16 f16x8 __attribute__((ext_vector_type(8)));
typedef float f32x4 __attribute__((ext_vector_type(4)));

__device__ __forceinline__ unsigned short f2h(float x) {
    _Float16 h = (_Float16)x;              // v_cvt_f16_f32, RNE
    return __builtin_bit_cast(unsigned short, h);
}
// Order-preserving (score,idx) packing: smaller score first, then smaller idx.
__device__ __forceinline__ unsigned long long pack_si(float s, int idx) {
    unsigned int u = __float_as_uint(s);
    unsigned int key = ((int)u < 0) ? ~u : (u | 0x80000000u);
    return ((unsigned long long)key << 32) | (unsigned int)idx;
}

// ---------------------------------------------------------------------------
// Kernel 1: emb prep — enorm (fp32 exact) + fp16 codebook e_h stored in a
// SWIZZLED layout: ushort index = code*128 + (dim ^ ((code&7)<<3)).
// global_load_lds copies tiles verbatim (cannot scatter), so the LDS
// bank swizzle is pre-baked into the global layout; reads apply the same
// XOR (both-sides-or-neither). Verified correct in R8 (passed, absmax =).
// ---------------------------------------------------------------------------
__global__ void emb_prep_kernel(const float* __restrict__ emb,
                                float* __restrict__ enorm,
                                unsigned short* __restrict__ e_h) {
    int wave = (blockIdx.x * blockDim.x + threadIdx.x) >> 6;
    int lane = threadIdx.x & 63;
    if (wave >= NK) return;
    const float* e = emb + (size_t)wave * ND;
    float a = e[lane];
    float b = e[lane + 64];
    const int m = (wave & 7) << 3;
    e_h[(size_t)wave * ND + (lane ^ m)] = f2h(a);
    e_h[(size_t)wave * ND + ((lane + 64) ^ m)] = f2h(b);
    float s = a * a + b * b;
#pragma unroll
    for (int off = 32; off > 0; off >>= 1) s += __shfl_down(s, off, 64);
    if (lane == 0) enorm[wave] = s;
}

// ---------------------------------------------------------------------------
// Kernel 2: MFMA argmin (R9).
// R8 diagnosis: (a) in-order vmcnt made the per-step global enorm loads wait
// the full staging latency (prefetch degenerated to sync); (b) 16 b128 LDS
// reads/wave-step -> 16.8M bank-conflict cycles; (c) 2 blocks/CU.
// R9: A-frags live in 32 VGPRs (read once; zh union-shares LDS with btile);
// enorm staged to LDS once (loop's only vmcnt = the 4 prefetch gll, drained
// at the barrier AFTER compute covers their latency); LDS 49.5KB -> 3
// blocks/CU. Scores bit-identical to R8's fast path.
// ---------------------------------------------------------------------------
#define ZST 136   // z staging row stride in ushort (272 B)

__global__ void
__attribute__((amdgpu_flat_work_group_size(256, 256)))
mfma_argmin_kernel(const float* __restrict__ z,
                   const unsigned short* __restrict__ e_h,
                   const float* __restrict__ enorm,
                   int* __restrict__ idx_out,
                   int* __restrict__ rcount,
                   int* __restrict__ rlist,
                   unsigned long long* __restrict__ rpart) {
    // ubuf: first used as z-staging (ZST layout, 8704 ushorts), then reused
    // as the double-buffered code tile: btile[b] = &ubuf[b*8192].
    __shared__ alignas(16) unsigned short ubuf[2 * 64 * ND];   // 32768 B
    __shared__ alignas(16) float enlds[NK];                    // 16384 B
    __shared__ float redb1[2 * 64];
    __shared__ float redb2[2 * 64];
    __shared__ int   redi1[2 * 64];

    const int bid = blockIdx.x;
    const int rowbase = bid * 64;
    const int t = threadIdx.x;
    const int lane = t & 63;
    const int wid = __builtin_amdgcn_readfirstlane(t >> 6);

    // ---- stage z rows (fp32 -> fp16) into ubuf (ZST layout) ----
    const float4* zg = (const float4*)(z + (size_t)rowbase * ND);
#pragma unroll
    for (int q = 0; q < 8; q++) {
        int i = t + 256 * q;               // 0..2047
        float4 v = zg[i];
        int r = i >> 5;
        int c4 = (i & 31) << 2;
        ushort4 hv = make_ushort4(f2h(v.x), f2h(v.y), f2h(v.z), f2h(v.w));
        *(ushort4*)&ubuf[r * ZST + c4] = hv;
    }
    // ---- stage enorm into LDS (removes vmcnt traffic from the hot loop) ----
#pragma unroll
    for (int q = 0; q < 4; q++) {
        int i = t + 256 * q;               // 0..1023
        *(float4*)&enlds[i * 4] = ((const float4*)enorm)[i];
    }
    __syncthreads();

    const int quad = lane >> 4;
    const int c = lane & 15;
    const int rh = wid >> 1;               // row half (rows rh*32..rh*32+31)
    const int ch = wid & 1;                // code half within each tile

    // ---- A-fragments -> registers (once; 8 frags = 32 VGPRs) ----
    f16x8 ar[2][4];
#pragma unroll
    for (int mi = 0; mi < 2; mi++)
#pragma unroll
        for (int kk = 0; kk < 4; kk++)
            ar[mi][kk] = *(const f16x8*)&ubuf[(rh * 32 + mi * 16 + c) * ZST + quad * 8 + kk * 32];
    __syncthreads();   // all frag reads done; ubuf may now be overwritten

    // ---- prologue: stage code-tile 0 into btile[0] (16 segs x 1 KB) ----
#pragma unroll
    for (int j = 0; j < 4; j++) {
        int seg = (wid << 2) + j;
        __builtin_amdgcn_global_load_lds(
            (const unsigned int*)(e_h + seg * 512 + lane * 8),
            (unsigned int*)&ubuf[seg * 512], 16, 0, 0);
    }
    __syncthreads();   // drain tile-0

    const int bswz = (c & 7) << 3;         // read-side swizzle (matches prep)
    const int bbase0 = (ch * 32 + c) * ND;

    float b1[2][4], b2[2][4];
    int i1[2][4];
#pragma unroll
    for (int mi = 0; mi < 2; mi++)
#pragma unroll
        for (int r = 0; r < 4; r++) { b1[mi][r] = 3.4e38f; b2[mi][r] = 3.4e38f; i1[mi][r] = 0; }

    for (int ts = 0; ts < NK / 64; ts++) {
        const int cur = ts & 1;
        const int curoff = cur << 13;      // cur * 8192 ushorts
        // issue next tile FIRST — its latency hides under this step's
        // compute; the pre-barrier vmcnt drain at step end completes it.
        if (ts < NK / 64 - 1) {
            const unsigned short* gt = e_h + (size_t)(ts + 1) * (64 * ND);
#pragma unroll
            for (int j = 0; j < 4; j++) {
                int seg = (wid << 2) + j;
                __builtin_amdgcn_global_load_lds(
                    (const unsigned int*)(gt + seg * 512 + lane * 8),
                    (unsigned int*)&ubuf[(curoff ^ 8192) + seg * 512], 16, 0, 0);
            }
        }

        // enorm from LDS (lgkmcnt — does not serialize against the prefetch)
        float en0 = enlds[ts * 64 + ch * 32 + c];
        float en1 = enlds[ts * 64 + ch * 32 + 16 + c];

        f32x4 acc[2][2];
#pragma unroll
        for (int mi = 0; mi < 2; mi++)
#pragma unroll
            for (int ni = 0; ni < 2; ni++) acc[mi][ni] = (f32x4){0.f, 0.f, 0.f, 0.f};

#pragma unroll
        for (int kk = 0; kk < 4; kk++) {
            const int doff = (quad * 8 + kk * 32) ^ bswz;
            f16x8 bv0 = *(const f16x8*)&ubuf[curoff + bbase0 + doff];
            f16x8 bv1 = *(const f16x8*)&ubuf[curoff + bbase0 + 16 * ND + doff];
            acc[0][0] = __builtin_amdgcn_mfma_f32_16x16x32_f16(ar[0][kk], bv0, acc[0][0], 0, 0, 0);
            acc[0][1] = __builtin_amdgcn_mfma_f32_16x16x32_f16(ar[0][kk], bv1, acc[0][1], 0, 0, 0);
            acc[1][0] = __builtin_amdgcn_mfma_f32_16x16x32_f16(ar[1][kk], bv0, acc[1][0], 0, 0, 0);
            acc[1][1] = __builtin_amdgcn_mfma_f32_16x16x32_f16(ar[1][kk], bv1, acc[1][1], 0, 0, 0);
        }

#pragma unroll
        for (int ni = 0; ni < 2; ni++) {
            const int n = ts * 64 + ch * 32 + ni * 16 + c;
            const float en = ni ? en1 : en0;
#pragma unroll
            for (int mi = 0; mi < 2; mi++)
#pragma unroll
                for (int r = 0; r < 4; r++) {
                    float s = fmaf(-2.0f, acc[mi][ni][r], en);
                    if (s < b1[mi][r]) { b2[mi][r] = b1[mi][r]; b1[mi][r] = s; i1[mi][r] = n; }
                    else if (s < b2[mi][r]) b2[mi][r] = s;
                }
        }

        // one barrier per step: next tile staged for everyone, and everyone
        // is done reading cur before it is overwritten next step.
        __syncthreads();
    }

    // ---- reduce over the 16 c-lanes (codes) within each wave ----
#pragma unroll
    for (int off = 1; off < 16; off <<= 1) {
#pragma unroll
        for (int mi = 0; mi < 2; mi++)
#pragma unroll
            for (int r = 0; r < 4; r++) {
                float ob1 = __shfl_xor(b1[mi][r], off, 64);
                float ob2 = __shfl_xor(b2[mi][r], off, 64);
                int oi1 = __shfl_xor(i1[mi][r], off, 64);
                float lo = fminf(b1[mi][r], ob1);
                float hi = fmaxf(b1[mi][r], ob1);
                b2[mi][r] = fminf(fminf(b2[mi][r], ob2), hi);
                i1[mi][r] = (ob1 < b1[mi][r]) ? oi1 : i1[mi][r];
                b1[mi][r] = lo;
            }
    }

    // ---- 2-way merge across code-halves ----
    if (c == 0) {
#pragma unroll
        for (int mi = 0; mi < 2; mi++)
#pragma unroll
            for (int r = 0; r < 4; r++) {
                int rowl = rh * 32 + mi * 16 + quad * 4 + r;
                redb1[ch * 64 + rowl] = b1[mi][r];
                redb2[ch * 64 + rowl] = b2[mi][r];
                redi1[ch * 64 + rowl] = i1[mi][r];
            }
    }
    __syncthreads();

    if (t < 64) {
        float B1 = redb1[t], B2 = redb2[t];
        int I1 = redi1[t];
        float ob1 = redb1[64 + t];
        float ob2 = redb2[64 + t];
        int oi1 = redi1[64 + t];
        float lo = fminf(B1, ob1);
        float hi = fmaxf(B1, ob1);
        B2 = fminf(fminf(B2, ob2), hi);
        I1 = (ob1 < B1) ? oi1 : I1;
        B1 = lo;
        idx_out[rowbase + t] = I1;
        if (B2 - B1 < MARGIN_F) {
            rpart[rowbase + t] = ~0ull;          // init for rescue atomicMin
            int p = atomicAdd(rcount, 1);
            rlist[p] = rowbase + t;
        }
    }
}

// ---------------------------------------------------------------------------
// Kernel 3: exact fp32 rescue (unchanged; reads fp32 emb, unswizzled).
// ---------------------------------------------------------------------------
#define RR 4        // rows per group
#define SC 512      // codes per slice
#define CH 64       // codes per staged chunk

__global__ void __launch_bounds__(256, 2)
rescue_kernel(const float* __restrict__ z,
              const float* __restrict__ emb,
              const float* __restrict__ enorm,
              const int* __restrict__ rcount,
              const int* __restrict__ rlist,
              unsigned long long* __restrict__ rpart) {
    __shared__ float2 ze[64 * RR];       // ze[d2*RR + r]
    __shared__ float2 es[64 * 65];       // es[d2*65 + code]
    __shared__ int ids[RR];

    const int t = threadIdx.x;
    const int cnt = *rcount;
    if (cnt == 0) return;
    const int ngrp = (cnt + RR - 1) / RR;
    const int nwork = ngrp * 8;

    const int r = t >> 6;                // 0..3 (== wave id)
    const int cl = t & 63;

    for (int g = blockIdx.x; g < nwork; g += gridDim.x) {
        const int gi = g >> 3;
        const int slice = g & 7;

        if (t < RR) {
            int j = gi * RR + t;
            ids[t] = rlist[j < cnt ? j : cnt - 1];
        }
        __syncthreads();                 // publish ids
        const int row = ids[r];
        ze[cl * RR + r] = ((const float2*)(z + (size_t)row * ND))[cl];  // coalesced

        unsigned long long bestp = ~0ull;
        const int kbase = slice * SC;

        for (int ch2 = 0; ch2 < SC / CH; ch2++) {
            __syncthreads();             // es safe to overwrite (also publishes ze on ch2==0)
#pragma unroll
            for (int q = 0; q < 16; q++) {
                int i = t + 256 * q;     // 0..4095
                int code = i >> 6;
                int d2 = i & 63;
                float2 v = ((const float2*)(emb + (size_t)(kbase + ch2 * CH + code) * ND))[d2];
                es[d2 * 65 + code] = v;
            }
            __syncthreads();

            int k = kbase + ch2 * CH + cl;
            float a0 = 0.f, a1 = 0.f, a2 = 0.f, a3 = 0.f;
#pragma unroll
            for (int d2 = 0; d2 < 64; d2 += 2) {
                float2 zv0 = ze[d2 * RR + r];            // wave-uniform
                float2 ev0 = es[d2 * 65 + cl];           // conflict-free
                float2 zv1 = ze[(d2 + 1) * RR + r];
                float2 ev1 = es[(d2 + 1) * 65 + cl];
                a0 = fmaf(zv0.x, ev0.x, a0);
                a1 = fmaf(zv0.y, ev0.y, a1);
                a2 = fmaf(zv1.x, ev1.x, a2);
                a3 = fmaf(zv1.y, ev1.y, a3);
            }
            float s = fmaf(-2.0f, (a0 + a1) + (a2 + a3), enorm[k]);
            unsigned long long p = pack_si(s, k);
            bestp = (p < bestp) ? p : bestp;
        }

        // wave-reduce min (all lanes in this wave share the same row)
#pragma unroll
        for (int off = 32; off > 0; off >>= 1) {
            unsigned long long o = __shfl_down(bestp, off, 64);
            bestp = (o < bestp) ? o : bestp;
        }
        if (cl == 0) atomicMin(&rpart[row], bestp);
        __syncthreads();                 // protect ids/ze before next g
    }
}

// ---------------------------------------------------------------------------
// Kernel 4: rescue finalize — unpack winning idx per rescue row.
// ---------------------------------------------------------------------------
__global__ void rescue_fin_kernel(const int* __restrict__ rcount,
                                  const int* __restrict__ rlist,
                                  const unsigned long long* __restrict__ rpart,
                                  int* __restrict__ idx_out) {
    const int cnt = *rcount;
    for (int i = blockIdx.x * blockDim.x + threadIdx.x; i < cnt;
         i += gridDim.x * blockDim.x) {
        int row = rlist[i];
        idx_out[row] = (int)(rpart[row] & 0xffffffffull);
    }
}

// ---------------------------------------------------------------------------
// Kernel 5: gather + loss partial + transposed write (unchanged).
// ---------------------------------------------------------------------------
__global__ void out_kernel(const float* __restrict__ z,
                           const float* __restrict__ emb,
                           const int* __restrict__ idx,
                           float* __restrict__ out,
                           float* __restrict__ losspart) {
    __shared__ float zq[64 * 129];
    __shared__ int ids[64];
    __shared__ float redl[4];

    const int bid = blockIdx.x;
    const int b = bid >> 6;
    const int h = bid & 63;
    const int rowbase = bid * 64;
    const int t = threadIdx.x;

    if (t < 64) ids[t] = idx[rowbase + t];
    __syncthreads();

    const int d = t & 127;
    const int w0 = t >> 7;
    float lsum = 0.f;
#pragma unroll
    for (int wq = 0; wq < 32; wq++) {
        int w = w0 + 2 * wq;
        float e = emb[(size_t)ids[w] * ND + d];
        float zv = z[((size_t)(rowbase + w)) * ND + d];
        float df = e - zv;
        lsum = fmaf(df, df, lsum);
        zq[w * 129 + d] = e;
    }
#pragma unroll
    for (int off = 32; off > 0; off >>= 1) lsum += __shfl_down(lsum, off, 64);
    if ((t & 63) == 0) redl[t >> 6] = lsum;
    __syncthreads();
    if (t == 0) losspart[bid] = redl[0] + redl[1] + redl[2] + redl[3];

    const int w = t & 63;
    const int dq = t >> 6;
#pragma unroll
    for (int dd0 = 0; dd0 < 32; dd0++) {
        int dd = dq + 4 * dd0;
        out[(((size_t)b * ND + dd) * NH + h) * NW + w] = zq[w * 129 + dd];
    }
}

// ---------------------------------------------------------------------------
// Kernel 6: final loss reduce
// ---------------------------------------------------------------------------
__global__ void loss_kernel(const float* __restrict__ losspart,
                            float* __restrict__ out) {
    __shared__ float redl[4];
    const int t = threadIdx.x;
    float s = 0.f;
#pragma unroll
    for (int i = 0; i < 4; i++) s += losspart[t + 256 * i];
#pragma unroll
    for (int off = 32; off > 0; off >>= 1) s += __shfl_down(s, off, 64);
    if ((t & 63) == 0) redl[t >> 6] = s;
    __syncthreads();
    if (t == 0) {
        float total = redl[0] + redl[1] + redl[2] + redl[3];
        out[OUT_ELEMS] = 1.25f * total / (float)OUT_ELEMS;
    }
}

// ---------------------------------------------------------------------------
extern "C" void kernel_launch(void* const* d_in, const int* in_sizes, int n_in,
                              void* d_out, int out_size, void* d_ws, size_t ws_size,
                              hipStream_t stream) {
    const float* z = (const float*)d_in[0];      // [16,64,64,128] fp32
    const float* emb = (const float*)d_in[1];    // [4096,128] fp32
    float* out = (float*)d_out;                  // 8388608 + 1 fp32

    char* ws = (char*)d_ws;
    int* ws_idx = (int*)ws;                                         // 256 KB
    float* ws_enorm = (float*)(ws + (256 << 10));                   // 16 KB
    float* ws_losspart = (float*)(ws + (272 << 10));                // 4 KB
    int* ws_rcount = (int*)(ws + (276 << 10));                      // 1 KB
    int* ws_rlist = (int*)(ws + (277 << 10));                       // 256 KB
    unsigned short* ws_eh = (unsigned short*)(ws + (533 << 10));    // 1 MB
    unsigned long long* ws_rpart = (unsigned long long*)(ws + (1557 << 10)); // 512 KB

    hipMemsetAsync(ws_rcount, 0, sizeof(int), stream);
    emb_prep_kernel<<<NK / 4, 256, 0, stream>>>(emb, ws_enorm, ws_eh);
    mfma_argmin_kernel<<<NROWS / 64, 256, 0, stream>>>(z, ws_eh, ws_enorm,
                                                       ws_idx, ws_rcount,
                                                       ws_rlist, ws_rpart);
    rescue_kernel<<<2048, 256, 0, stream>>>(z, emb, ws_enorm, ws_rcount,
                                            ws_rlist, ws_rpart);
    rescue_fin_kernel<<<64, 256, 0, stream>>>(ws_rcount, ws_rlist, ws_rpart,
                                              ws_idx);
    out_kernel<<<NB * NH, 256, 0, stream>>>(z, emb, ws_idx, out, ws_losspart);
    loss_kernel<<<1, 256, 0, stream>>>(ws_losspart, out);
}

// Round 10
// 312.095 us; speedup vs baseline: 1.9048x; 1.2425x over previous
//
#include <hip/hip_runtime.h>

// Problem constants
#define NB 16
#define NH 64
#define NW 64
#define ND 128
#define NK 4096
#define NROWS (NB * NH * NW)        // 65536
#define OUT_ELEMS (NB * ND * NH * NW)  // 8388608
// fp16 single-term fast path: score-gap error sigma ~= 0.013; margin 0.10
// ~= 8 sigma. Exact-fp32 rescue handles everything below the margin.
#define MARGIN_F 0.10f

typedef _Float16 f16x8 __attribute__((ext_vector_type(8)));
typedef float f32x4 __attribute__((ext_vector_type(4)));

__device__ __forceinline__ unsigned short f2h(float x) {
    _Float16 h = (_Float16)x;              // v_cvt_f16_f32, RNE
    return __builtin_bit_cast(unsigned short, h);
}
// Order-preserving (score,idx) packing: smaller score first, then smaller idx.
__device__ __forceinline__ unsigned long long pack_si(float s, int idx) {
    unsigned int u = __float_as_uint(s);
    unsigned int key = ((int)u < 0) ? ~u : (u | 0x80000000u);
    return ((unsigned long long)key << 32) | (unsigned int)idx;
}

// ---------------------------------------------------------------------------
// Kernel 1: emb prep — enorm (fp32 exact) + fp16 codebook e_h stored in a
// SWIZZLED layout: ushort index = code*128 + (dim ^ ((code&7)<<3)).
// global_load_lds copies tiles verbatim (cannot scatter), so the LDS bank
// swizzle is pre-baked into the global layout; reads apply the same XOR.
// Verified correct R8/R9 (passed, absmax unchanged).
// ---------------------------------------------------------------------------
__global__ void emb_prep_kernel(const float* __restrict__ emb,
                                float* __restrict__ enorm,
                                unsigned short* __restrict__ e_h) {
    int wave = (blockIdx.x * blockDim.x + threadIdx.x) >> 6;
    int lane = threadIdx.x & 63;
    if (wave >= NK) return;
    const float* e = emb + (size_t)wave * ND;
    float a = e[lane];
    float b = e[lane + 64];
    const int m = (wave & 7) << 3;
    e_h[(size_t)wave * ND + (lane ^ m)] = f2h(a);
    e_h[(size_t)wave * ND + ((lane + 64) ^ m)] = f2h(b);
    float s = a * a + b * b;
#pragma unroll
    for (int off = 32; off > 0; off >>= 1) s += __shfl_down(s, off, 64);
    if (lane == 0) enorm[wave] = s;
}

// ---------------------------------------------------------------------------
// Kernel 2: MFMA argmin (R10).
// R9 counters: Occ 23% (2 blocks/CU at 50.7KB LDS), busy 55%, stall 45% —
// the end-of-step vmcnt(0)+barrier drain with only 2 waves/SIMD to cover.
// R10: LDS diet for occupancy. enlds (16KB) removed; the two enorm scalars
// are software-pipelined in REGISTERS: en(i+1) loaded at step i, consumed
// at step i+1 (strictly after the end-of-step drain -> immune to the R8
// in-order-vmcnt serialization; costs 4 VGPRs). LDS 50.7KB -> 34.3KB ->
// 4 blocks/CU, 16 waves/CU. A-frags in regs; tile double-buffer unchanged.
// ---------------------------------------------------------------------------
#define ZST 136   // z staging row stride in ushort (272 B)

__global__ void
__attribute__((amdgpu_flat_work_group_size(256, 256)))
mfma_argmin_kernel(const float* __restrict__ z,
                   const unsigned short* __restrict__ e_h,
                   const float* __restrict__ enorm,
                   int* __restrict__ idx_out,
                   int* __restrict__ rcount,
                   int* __restrict__ rlist,
                   unsigned long long* __restrict__ rpart) {
    // ubuf: first used as z-staging (ZST layout, 8704 ushorts), then reused
    // as the double-buffered code tile: btile[b] = &ubuf[b*8192].
    __shared__ alignas(16) unsigned short ubuf[2 * 64 * ND];   // 32768 B
    __shared__ float redb1[2 * 64];
    __shared__ float redb2[2 * 64];
    __shared__ int   redi1[2 * 64];

    const int bid = blockIdx.x;
    const int rowbase = bid * 64;
    const int t = threadIdx.x;
    const int lane = t & 63;
    const int wid = __builtin_amdgcn_readfirstlane(t >> 6);

    // ---- stage z rows (fp32 -> fp16) into ubuf (ZST layout) ----
    const float4* zg = (const float4*)(z + (size_t)rowbase * ND);
#pragma unroll
    for (int q = 0; q < 8; q++) {
        int i = t + 256 * q;               // 0..2047
        float4 v = zg[i];
        int r = i >> 5;
        int c4 = (i & 31) << 2;
        ushort4 hv = make_ushort4(f2h(v.x), f2h(v.y), f2h(v.z), f2h(v.w));
        *(ushort4*)&ubuf[r * ZST + c4] = hv;
    }
    __syncthreads();

    const int quad = lane >> 4;
    const int c = lane & 15;
    const int rh = wid >> 1;               // row half (rows rh*32..rh*32+31)
    const int ch = wid & 1;                // code half within each tile

    // ---- A-fragments -> registers (once; 8 frags = 32 VGPRs) ----
    f16x8 ar[2][4];
#pragma unroll
    for (int mi = 0; mi < 2; mi++)
#pragma unroll
        for (int kk = 0; kk < 4; kk++)
            ar[mi][kk] = *(const f16x8*)&ubuf[(rh * 32 + mi * 16 + c) * ZST + quad * 8 + kk * 32];
    __syncthreads();   // all frag reads done; ubuf may now be overwritten

    // ---- prologue: stage code-tile 0 + load en(0) into regs ----
#pragma unroll
    for (int j = 0; j < 4; j++) {
        int seg = (wid << 2) + j;
        __builtin_amdgcn_global_load_lds(
            (const unsigned int*)(e_h + seg * 512 + lane * 8),
            (unsigned int*)&ubuf[seg * 512], 16, 0, 0);
    }
    float en0 = enorm[ch * 32 + c];
    float en1 = enorm[ch * 32 + 16 + c];
    __syncthreads();   // drain tile-0 (+ en(0) completes under the drain)

    const int bswz = (c & 7) << 3;         // read-side swizzle (matches prep)
    const int bbase0 = (ch * 32 + c) * ND;

    float b1[2][4], b2[2][4];
    int i1[2][4];
#pragma unroll
    for (int mi = 0; mi < 2; mi++)
#pragma unroll
        for (int r = 0; r < 4; r++) { b1[mi][r] = 3.4e38f; b2[mi][r] = 3.4e38f; i1[mi][r] = 0; }

    for (int ts = 0; ts < NK / 64; ts++) {
        const int cur = ts & 1;
        const int curoff = cur << 13;      // cur * 8192 ushorts

        // pipeline: issue next step's en loads + tile stage FIRST; both are
        // consumed only AFTER the end-of-step drain, so their latency hides
        // under this step's compute regardless of vmcnt retirement order.
        float nen0 = 0.f, nen1 = 0.f;
        if (ts < NK / 64 - 1) {
            nen0 = enorm[(ts + 1) * 64 + ch * 32 + c];
            nen1 = enorm[(ts + 1) * 64 + ch * 32 + 16 + c];
            const unsigned short* gt = e_h + (size_t)(ts + 1) * (64 * ND);
#pragma unroll
            for (int j = 0; j < 4; j++) {
                int seg = (wid << 2) + j;
                __builtin_amdgcn_global_load_lds(
                    (const unsigned int*)(gt + seg * 512 + lane * 8),
                    (unsigned int*)&ubuf[(curoff ^ 8192) + seg * 512], 16, 0, 0);
            }
        }

        f32x4 acc[2][2];
#pragma unroll
        for (int mi = 0; mi < 2; mi++)
#pragma unroll
            for (int ni = 0; ni < 2; ni++) acc[mi][ni] = (f32x4){0.f, 0.f, 0.f, 0.f};

#pragma unroll
        for (int kk = 0; kk < 4; kk++) {
            const int doff = (quad * 8 + kk * 32) ^ bswz;
            f16x8 bv0 = *(const f16x8*)&ubuf[curoff + bbase0 + doff];
            f16x8 bv1 = *(const f16x8*)&ubuf[curoff + bbase0 + 16 * ND + doff];
            acc[0][0] = __builtin_amdgcn_mfma_f32_16x16x32_f16(ar[0][kk], bv0, acc[0][0], 0, 0, 0);
            acc[0][1] = __builtin_amdgcn_mfma_f32_16x16x32_f16(ar[0][kk], bv1, acc[0][1], 0, 0, 0);
            acc[1][0] = __builtin_amdgcn_mfma_f32_16x16x32_f16(ar[1][kk], bv0, acc[1][0], 0, 0, 0);
            acc[1][1] = __builtin_amdgcn_mfma_f32_16x16x32_f16(ar[1][kk], bv1, acc[1][1], 0, 0, 0);
        }

#pragma unroll
        for (int ni = 0; ni < 2; ni++) {
            const int n = ts * 64 + ch * 32 + ni * 16 + c;
            const float en = ni ? en1 : en0;
#pragma unroll
            for (int mi = 0; mi < 2; mi++)
#pragma unroll
                for (int r = 0; r < 4; r++) {
                    float s = fmaf(-2.0f, acc[mi][ni][r], en);
                    if (s < b1[mi][r]) { b2[mi][r] = b1[mi][r]; b1[mi][r] = s; i1[mi][r] = n; }
                    else if (s < b2[mi][r]) b2[mi][r] = s;
                }
        }

        // one barrier per step: next tile staged for everyone, and everyone
        // is done reading cur before it is overwritten next step.
        __syncthreads();
        en0 = nen0;
        en1 = nen1;
    }

    // ---- reduce over the 16 c-lanes (codes) within each wave ----
#pragma unroll
    for (int off = 1; off < 16; off <<= 1) {
#pragma unroll
        for (int mi = 0; mi < 2; mi++)
#pragma unroll
            for (int r = 0; r < 4; r++) {
                float ob1 = __shfl_xor(b1[mi][r], off, 64);
                float ob2 = __shfl_xor(b2[mi][r], off, 64);
                int oi1 = __shfl_xor(i1[mi][r], off, 64);
                float lo = fminf(b1[mi][r], ob1);
                float hi = fmaxf(b1[mi][r], ob1);
                b2[mi][r] = fminf(fminf(b2[mi][r], ob2), hi);
                i1[mi][r] = (ob1 < b1[mi][r]) ? oi1 : i1[mi][r];
                b1[mi][r] = lo;
            }
    }

    // ---- 2-way merge across code-halves ----
    if (c == 0) {
#pragma unroll
        for (int mi = 0; mi < 2; mi++)
#pragma unroll
            for (int r = 0; r < 4; r++) {
                int rowl = rh * 32 + mi * 16 + quad * 4 + r;
                redb1[ch * 64 + rowl] = b1[mi][r];
                redb2[ch * 64 + rowl] = b2[mi][r];
                redi1[ch * 64 + rowl] = i1[mi][r];
            }
    }
    __syncthreads();

    if (t < 64) {
        float B1 = redb1[t], B2 = redb2[t];
        int I1 = redi1[t];
        float ob1 = redb1[64 + t];
        float ob2 = redb2[64 + t];
        int oi1 = redi1[64 + t];
        float lo = fminf(B1, ob1);
        float hi = fmaxf(B1, ob1);
        B2 = fminf(fminf(B2, ob2), hi);
        I1 = (ob1 < B1) ? oi1 : I1;
        B1 = lo;
        idx_out[rowbase + t] = I1;
        if (B2 - B1 < MARGIN_F) {
            rpart[rowbase + t] = ~0ull;          // init for rescue atomicMin
            int p = atomicAdd(rcount, 1);
            rlist[p] = rowbase + t;
        }
    }
}

// ---------------------------------------------------------------------------
// Kernel 3: exact fp32 rescue (unchanged; reads fp32 emb, unswizzled).
// ---------------------------------------------------------------------------
#define RR 4        // rows per group
#define SC 512      // codes per slice
#define CH 64       // codes per staged chunk

__global__ void __launch_bounds__(256, 2)
rescue_kernel(const float* __restrict__ z,
              const float* __restrict__ emb,
              const float* __restrict__ enorm,
              const int* __restrict__ rcount,
              const int* __restrict__ rlist,
              unsigned long long* __restrict__ rpart) {
    __shared__ float2 ze[64 * RR];       // ze[d2*RR + r]
    __shared__ float2 es[64 * 65];       // es[d2*65 + code]
    __shared__ int ids[RR];

    const int t = threadIdx.x;
    const int cnt = *rcount;
    if (cnt == 0) return;
    const int ngrp = (cnt + RR - 1) / RR;
    const int nwork = ngrp * 8;

    const int r = t >> 6;                // 0..3 (== wave id)
    const int cl = t & 63;

    for (int g = blockIdx.x; g < nwork; g += gridDim.x) {
        const int gi = g >> 3;
        const int slice = g & 7;

        if (t < RR) {
            int j = gi * RR + t;
            ids[t] = rlist[j < cnt ? j : cnt - 1];
        }
        __syncthreads();                 // publish ids
        const int row = ids[r];
        ze[cl * RR + r] = ((const float2*)(z + (size_t)row * ND))[cl];  // coalesced

        unsigned long long bestp = ~0ull;
        const int kbase = slice * SC;

        for (int ch2 = 0; ch2 < SC / CH; ch2++) {
            __syncthreads();             // es safe to overwrite (also publishes ze on ch2==0)
#pragma unroll
            for (int q = 0; q < 16; q++) {
                int i = t + 256 * q;     // 0..4095
                int code = i >> 6;
                int d2 = i & 63;
                float2 v = ((const float2*)(emb + (size_t)(kbase + ch2 * CH + code) * ND))[d2];
                es[d2 * 65 + code] = v;
            }
            __syncthreads();

            int k = kbase + ch2 * CH + cl;
            float a0 = 0.f, a1 = 0.f, a2 = 0.f, a3 = 0.f;
#pragma unroll
            for (int d2 = 0; d2 < 64; d2 += 2) {
                float2 zv0 = ze[d2 * RR + r];            // wave-uniform
                float2 ev0 = es[d2 * 65 + cl];           // conflict-free
                float2 zv1 = ze[(d2 + 1) * RR + r];
                float2 ev1 = es[(d2 + 1) * 65 + cl];
                a0 = fmaf(zv0.x, ev0.x, a0);
                a1 = fmaf(zv0.y, ev0.y, a1);
                a2 = fmaf(zv1.x, ev1.x, a2);
                a3 = fmaf(zv1.y, ev1.y, a3);
            }
            float s = fmaf(-2.0f, (a0 + a1) + (a2 + a3), enorm[k]);
            unsigned long long p = pack_si(s, k);
            bestp = (p < bestp) ? p : bestp;
        }

        // wave-reduce min (all lanes in this wave share the same row)
#pragma unroll
        for (int off = 32; off > 0; off >>= 1) {
            unsigned long long o = __shfl_down(bestp, off, 64);
            bestp = (o < bestp) ? o : bestp;
        }
        if (cl == 0) atomicMin(&rpart[row], bestp);
        __syncthreads();                 // protect ids/ze before next g
    }
}

// ---------------------------------------------------------------------------
// Kernel 4: rescue finalize — unpack winning idx per rescue row.
// ---------------------------------------------------------------------------
__global__ void rescue_fin_kernel(const int* __restrict__ rcount,
                                  const int* __restrict__ rlist,
                                  const unsigned long long* __restrict__ rpart,
                                  int* __restrict__ idx_out) {
    const int cnt = *rcount;
    for (int i = blockIdx.x * blockDim.x + threadIdx.x; i < cnt;
         i += gridDim.x * blockDim.x) {
        int row = rlist[i];
        idx_out[row] = (int)(rpart[row] & 0xffffffffull);
    }
}

// ---------------------------------------------------------------------------
// Kernel 5: gather + loss partial + transposed write (unchanged).
// ---------------------------------------------------------------------------
__global__ void out_kernel(const float* __restrict__ z,
                           const float* __restrict__ emb,
                           const int* __restrict__ idx,
                           float* __restrict__ out,
                           float* __restrict__ losspart) {
    __shared__ float zq[64 * 129];
    __shared__ int ids[64];
    __shared__ float redl[4];

    const int bid = blockIdx.x;
    const int b = bid >> 6;
    const int h = bid & 63;
    const int rowbase = bid * 64;
    const int t = threadIdx.x;

    if (t < 64) ids[t] = idx[rowbase + t];
    __syncthreads();

    const int d = t & 127;
    const int w0 = t >> 7;
    float lsum = 0.f;
#pragma unroll
    for (int wq = 0; wq < 32; wq++) {
        int w = w0 + 2 * wq;
        float e = emb[(size_t)ids[w] * ND + d];
        float zv = z[((size_t)(rowbase + w)) * ND + d];
        float df = e - zv;
        lsum = fmaf(df, df, lsum);
        zq[w * 129 + d] = e;
    }
#pragma unroll
    for (int off = 32; off > 0; off >>= 1) lsum += __shfl_down(lsum, off, 64);
    if ((t & 63) == 0) redl[t >> 6] = lsum;
    __syncthreads();
    if (t == 0) losspart[bid] = redl[0] + redl[1] + redl[2] + redl[3];

    const int w = t & 63;
    const int dq = t >> 6;
#pragma unroll
    for (int dd0 = 0; dd0 < 32; dd0++) {
        int dd = dq + 4 * dd0;
        out[(((size_t)b * ND + dd) * NH + h) * NW + w] = zq[w * 129 + dd];
    }
}

// ---------------------------------------------------------------------------
// Kernel 6: final loss reduce
// ---------------------------------------------------------------------------
__global__ void loss_kernel(const float* __restrict__ losspart,
                            float* __restrict__ out) {
    __shared__ float redl[4];
    const int t = threadIdx.x;
    float s = 0.f;
#pragma unroll
    for (int i = 0; i < 4; i++) s += losspart[t + 256 * i];
#pragma unroll
    for (int off = 32; off > 0; off >>= 1) s += __shfl_down(s, off, 64);
    if ((t & 63) == 0) redl[t >> 6] = s;
    __syncthreads();
    if (t == 0) {
        float total = redl[0] + redl[1] + redl[2] + redl[3];
        out[OUT_ELEMS] = 1.25f * total / (float)OUT_ELEMS;
    }
}

// ---------------------------------------------------------------------------
extern "C" void kernel_launch(void* const* d_in, const int* in_sizes, int n_in,
                              void* d_out, int out_size, void* d_ws, size_t ws_size,
                              hipStream_t stream) {
    const float* z = (const float*)d_in[0];      // [16,64,64,128] fp32
    const float* emb = (const float*)d_in[1];    // [4096,128] fp32
    float* out = (float*)d_out;                  // 8388608 + 1 fp32

    char* ws = (char*)d_ws;
    int* ws_idx = (int*)ws;                                         // 256 KB
    float* ws_enorm = (float*)(ws + (256 << 10));                   // 16 KB
    float* ws_losspart = (float*)(ws + (272 << 10));                // 4 KB
    int* ws_rcount = (int*)(ws + (276 << 10));                      // 1 KB
    int* ws_rlist = (int*)(ws + (277 << 10));                       // 256 KB
    unsigned short* ws_eh = (unsigned short*)(ws + (533 << 10));    // 1 MB
    unsigned long long* ws_rpart = (unsigned long long*)(ws + (1557 << 10)); // 512 KB

    hipMemsetAsync(ws_rcount, 0, sizeof(int), stream);
    emb_prep_kernel<<<NK / 4, 256, 0, stream>>>(emb, ws_enorm, ws_eh);
    mfma_argmin_kernel<<<NROWS / 64, 256, 0, stream>>>(z, ws_eh, ws_enorm,
                                                       ws_idx, ws_rcount,
                                                       ws_rlist, ws_rpart);
    rescue_kernel<<<2048, 256, 0, stream>>>(z, emb, ws_enorm, ws_rcount,
                                            ws_rlist, ws_rpart);
    rescue_fin_kernel<<<64, 256, 0, stream>>>(ws_rcount, ws_rlist, ws_rpart,
                                              ws_idx);
    out_kernel<<<NB * NH, 256, 0, stream>>>(z, emb, ws_idx, out, ws_losspart);
    loss_kernel<<<1, 256, 0, stream>>>(ws_losspart, out);
}

// Round 11
// 307.882 us; speedup vs baseline: 1.9308x; 1.0137x over previous
//
#include <hip/hip_runtime.h>

// Problem constants
#define NB 16
#define NH 64
#define NW 64
#define ND 128
#define NK 4096
#define NROWS (NB * NH * NW)        // 65536
#define OUT_ELEMS (NB * ND * NH * NW)  // 8388608
// fp16 single-term fast path: score-gap error sigma ~= 0.013; margin 0.10
// ~= 8 sigma. Exact-fp32 rescue handles everything below the margin.
#define MARGIN_F 0.10f

typedef _Float16 f16x8 __attribute__((ext_vector_type(8)));
typedef float f32x4 __attribute__((ext_vector_type(4)));

__device__ __forceinline__ unsigned short f2h(float x) {
    _Float16 h = (_Float16)x;              // v_cvt_f16_f32, RNE
    return __builtin_bit_cast(unsigned short, h);
}
// Order-preserving (score,idx) packing: smaller score first, then smaller idx.
__device__ __forceinline__ unsigned long long pack_si(float s, int idx) {
    unsigned int u = __float_as_uint(s);
    unsigned int key = ((int)u < 0) ? ~u : (u | 0x80000000u);
    return ((unsigned long long)key << 32) | (unsigned int)idx;
}

// ---------------------------------------------------------------------------
// Kernel 1: emb prep — enorm (fp32 exact) + fp16 codebook e_h stored in a
// SWIZZLED layout: ushort index = code*128 + (dim ^ ((code&7)<<3)).
// global_load_lds copies tiles verbatim (cannot scatter), so the LDS bank
// swizzle is pre-baked into the global layout; reads apply the same XOR.
// ---------------------------------------------------------------------------
__global__ void emb_prep_kernel(const float* __restrict__ emb,
                                float* __restrict__ enorm,
                                unsigned short* __restrict__ e_h) {
    int wave = (blockIdx.x * blockDim.x + threadIdx.x) >> 6;
    int lane = threadIdx.x & 63;
    if (wave >= NK) return;
    const float* e = emb + (size_t)wave * ND;
    float a = e[lane];
    float b = e[lane + 64];
    const int m = (wave & 7) << 3;
    e_h[(size_t)wave * ND + (lane ^ m)] = f2h(a);
    e_h[(size_t)wave * ND + ((lane + 64) ^ m)] = f2h(b);
    float s = a * a + b * b;
#pragma unroll
    for (int off = 32; off > 0; off >>= 1) s += __shfl_down(s, off, 64);
    if (lane == 0) enorm[wave] = s;
}

// ---------------------------------------------------------------------------
// Kernel 2: MFMA argmin (R11).
// R10 result: 125us, Occ 42%, VALU 72% + MFMA 23% = 95% issue-bound -> thin
// the VALU epilogue. R11 (one change, 3 coupled parts):
//  (a) acc init = -0.5*en (en already in pipelined regs) -> MFMA emits
//      q = z.e - 0.5*en; argmin s == argmax q (s = -2q, exact scale) ->
//      the 16 per-score fmaf disappear;
//  (b) branch-free top-2-MAX update, 5 ops/score (no predicated chain);
//  (c) margin check: 2*(B1-B2) < MARGIN (same numerics, scaled).
// Rescue path unchanged -> near-tie rounding flips still exactly covered.
// ---------------------------------------------------------------------------
#define ZST 136   // z staging row stride in ushort (272 B)

__global__ void
__attribute__((amdgpu_flat_work_group_size(256, 256)))
mfma_argmin_kernel(const float* __restrict__ z,
                   const unsigned short* __restrict__ e_h,
                   const float* __restrict__ enorm,
                   int* __restrict__ idx_out,
                   int* __restrict__ rcount,
                   int* __restrict__ rlist,
                   unsigned long long* __restrict__ rpart) {
    // ubuf: first used as z-staging (ZST layout), then reused as the
    // double-buffered code tile: btile[b] = &ubuf[b*8192].
    __shared__ alignas(16) unsigned short ubuf[2 * 64 * ND];   // 32768 B
    __shared__ float redb1[2 * 64];
    __shared__ float redb2[2 * 64];
    __shared__ int   redi1[2 * 64];

    const int bid = blockIdx.x;
    const int rowbase = bid * 64;
    const int t = threadIdx.x;
    const int lane = t & 63;
    const int wid = __builtin_amdgcn_readfirstlane(t >> 6);

    // ---- stage z rows (fp32 -> fp16) into ubuf (ZST layout) ----
    const float4* zg = (const float4*)(z + (size_t)rowbase * ND);
#pragma unroll
    for (int q = 0; q < 8; q++) {
        int i = t + 256 * q;               // 0..2047
        float4 v = zg[i];
        int r = i >> 5;
        int c4 = (i & 31) << 2;
        ushort4 hv = make_ushort4(f2h(v.x), f2h(v.y), f2h(v.z), f2h(v.w));
        *(ushort4*)&ubuf[r * ZST + c4] = hv;
    }
    __syncthreads();

    const int quad = lane >> 4;
    const int c = lane & 15;
    const int rh = wid >> 1;               // row half (rows rh*32..rh*32+31)
    const int ch = wid & 1;                // code half within each tile

    // ---- A-fragments -> registers (once; 8 frags = 32 VGPRs) ----
    f16x8 ar[2][4];
#pragma unroll
    for (int mi = 0; mi < 2; mi++)
#pragma unroll
        for (int kk = 0; kk < 4; kk++)
            ar[mi][kk] = *(const f16x8*)&ubuf[(rh * 32 + mi * 16 + c) * ZST + quad * 8 + kk * 32];
    __syncthreads();   // all frag reads done; ubuf may now be overwritten

    // ---- prologue: stage code-tile 0 + load en(0) into regs ----
#pragma unroll
    for (int j = 0; j < 4; j++) {
        int seg = (wid << 2) + j;
        __builtin_amdgcn_global_load_lds(
            (const unsigned int*)(e_h + seg * 512 + lane * 8),
            (unsigned int*)&ubuf[seg * 512], 16, 0, 0);
    }
    float en0 = enorm[ch * 32 + c];
    float en1 = enorm[ch * 32 + 16 + c];
    __syncthreads();   // drain tile-0 (+ en(0) completes under the drain)

    const int bswz = (c & 7) << 3;         // read-side swizzle (matches prep)
    const int bbase0 = (ch * 32 + c) * ND;

    // max-form top-2: b1 = max q, b2 = second-max q (invariant b1 >= b2)
    float b1[2][4], b2[2][4];
    int i1[2][4];
#pragma unroll
    for (int mi = 0; mi < 2; mi++)
#pragma unroll
        for (int r = 0; r < 4; r++) { b1[mi][r] = -3.4e38f; b2[mi][r] = -3.4e38f; i1[mi][r] = 0; }

    for (int ts = 0; ts < NK / 64; ts++) {
        const int cur = ts & 1;
        const int curoff = cur << 13;      // cur * 8192 ushorts

        // pipeline: issue next step's en loads + tile stage FIRST; both are
        // consumed only AFTER the end-of-step drain, so their latency hides
        // under this step's compute regardless of vmcnt retirement order.
        float nen0 = 0.f, nen1 = 0.f;
        if (ts < NK / 64 - 1) {
            nen0 = enorm[(ts + 1) * 64 + ch * 32 + c];
            nen1 = enorm[(ts + 1) * 64 + ch * 32 + 16 + c];
            const unsigned short* gt = e_h + (size_t)(ts + 1) * (64 * ND);
#pragma unroll
            for (int j = 0; j < 4; j++) {
                int seg = (wid << 2) + j;
                __builtin_amdgcn_global_load_lds(
                    (const unsigned int*)(gt + seg * 512 + lane * 8),
                    (unsigned int*)&ubuf[(curoff ^ 8192) + seg * 512], 16, 0, 0);
            }
        }

        // acc init = -0.5*en  ->  MFMA output q = z.e - 0.5*en
        const float h0 = -0.5f * en0;
        const float h1 = -0.5f * en1;
        f32x4 acc[2][2];
#pragma unroll
        for (int mi = 0; mi < 2; mi++) {
            acc[mi][0] = (f32x4){h0, h0, h0, h0};
            acc[mi][1] = (f32x4){h1, h1, h1, h1};
        }

#pragma unroll
        for (int kk = 0; kk < 4; kk++) {
            const int doff = (quad * 8 + kk * 32) ^ bswz;
            f16x8 bv0 = *(const f16x8*)&ubuf[curoff + bbase0 + doff];
            f16x8 bv1 = *(const f16x8*)&ubuf[curoff + bbase0 + 16 * ND + doff];
            acc[0][0] = __builtin_amdgcn_mfma_f32_16x16x32_f16(ar[0][kk], bv0, acc[0][0], 0, 0, 0);
            acc[0][1] = __builtin_amdgcn_mfma_f32_16x16x32_f16(ar[0][kk], bv1, acc[0][1], 0, 0, 0);
            acc[1][0] = __builtin_amdgcn_mfma_f32_16x16x32_f16(ar[1][kk], bv0, acc[1][0], 0, 0, 0);
            acc[1][1] = __builtin_amdgcn_mfma_f32_16x16x32_f16(ar[1][kk], bv1, acc[1][1], 0, 0, 0);
        }

#pragma unroll
        for (int ni = 0; ni < 2; ni++) {
            const int n = ts * 64 + ch * 32 + ni * 16 + c;
#pragma unroll
            for (int mi = 0; mi < 2; mi++)
#pragma unroll
                for (int r = 0; r < 4; r++) {
                    float q = acc[mi][ni][r];
                    // branch-free top-2-max insert (5 VALU ops)
                    b2[mi][r] = fmaxf(b2[mi][r], fminf(b1[mi][r], q));
                    i1[mi][r] = (q > b1[mi][r]) ? n : i1[mi][r];
                    b1[mi][r] = fmaxf(b1[mi][r], q);
                }
        }

        // one barrier per step: next tile staged for everyone, and everyone
        // is done reading cur before it is overwritten next step.
        __syncthreads();
        en0 = nen0;
        en1 = nen1;
    }

    // ---- reduce over the 16 c-lanes (codes) within each wave (max-form) ----
#pragma unroll
    for (int off = 1; off < 16; off <<= 1) {
#pragma unroll
        for (int mi = 0; mi < 2; mi++)
#pragma unroll
            for (int r = 0; r < 4; r++) {
                float ob1 = __shfl_xor(b1[mi][r], off, 64);
                float ob2 = __shfl_xor(b2[mi][r], off, 64);
                int oi1 = __shfl_xor(i1[mi][r], off, 64);
                float hi = fmaxf(b1[mi][r], ob1);
                float lo = fminf(b1[mi][r], ob1);
                b2[mi][r] = fmaxf(fmaxf(b2[mi][r], ob2), lo);
                i1[mi][r] = (ob1 > b1[mi][r]) ? oi1 : i1[mi][r];
                b1[mi][r] = hi;
            }
    }

    // ---- 2-way merge across code-halves ----
    if (c == 0) {
#pragma unroll
        for (int mi = 0; mi < 2; mi++)
#pragma unroll
            for (int r = 0; r < 4; r++) {
                int rowl = rh * 32 + mi * 16 + quad * 4 + r;
                redb1[ch * 64 + rowl] = b1[mi][r];
                redb2[ch * 64 + rowl] = b2[mi][r];
                redi1[ch * 64 + rowl] = i1[mi][r];
            }
    }
    __syncthreads();

    if (t < 64) {
        float B1 = redb1[t], B2 = redb2[t];
        int I1 = redi1[t];
        float ob1 = redb1[64 + t];
        float ob2 = redb2[64 + t];
        int oi1 = redi1[64 + t];
        float hi = fmaxf(B1, ob1);
        float lo = fminf(B1, ob1);
        B2 = fmaxf(fmaxf(B2, ob2), lo);
        I1 = (ob1 > B1) ? oi1 : I1;
        B1 = hi;
        idx_out[rowbase + t] = I1;
        // score gap = -2*B2q - (-2*B1q) = 2*(B1q - B2q)
        if (2.0f * (B1 - B2) < MARGIN_F) {
            rpart[rowbase + t] = ~0ull;          // init for rescue atomicMin
            int p = atomicAdd(rcount, 1);
            rlist[p] = rowbase + t;
        }
    }
}

// ---------------------------------------------------------------------------
// Kernel 3: exact fp32 rescue (unchanged; reads fp32 emb, unswizzled).
// ---------------------------------------------------------------------------
#define RR 4        // rows per group
#define SC 512      // codes per slice
#define CH 64       // codes per staged chunk

__global__ void __launch_bounds__(256, 2)
rescue_kernel(const float* __restrict__ z,
              const float* __restrict__ emb,
              const float* __restrict__ enorm,
              const int* __restrict__ rcount,
              const int* __restrict__ rlist,
              unsigned long long* __restrict__ rpart) {
    __shared__ float2 ze[64 * RR];       // ze[d2*RR + r]
    __shared__ float2 es[64 * 65];       // es[d2*65 + code]
    __shared__ int ids[RR];

    const int t = threadIdx.x;
    const int cnt = *rcount;
    if (cnt == 0) return;
    const int ngrp = (cnt + RR - 1) / RR;
    const int nwork = ngrp * 8;

    const int r = t >> 6;                // 0..3 (== wave id)
    const int cl = t & 63;

    for (int g = blockIdx.x; g < nwork; g += gridDim.x) {
        const int gi = g >> 3;
        const int slice = g & 7;

        if (t < RR) {
            int j = gi * RR + t;
            ids[t] = rlist[j < cnt ? j : cnt - 1];
        }
        __syncthreads();                 // publish ids
        const int row = ids[r];
        ze[cl * RR + r] = ((const float2*)(z + (size_t)row * ND))[cl];  // coalesced

        unsigned long long bestp = ~0ull;
        const int kbase = slice * SC;

        for (int ch2 = 0; ch2 < SC / CH; ch2++) {
            __syncthreads();             // es safe to overwrite (also publishes ze on ch2==0)
#pragma unroll
            for (int q = 0; q < 16; q++) {
                int i = t + 256 * q;     // 0..4095
                int code = i >> 6;
                int d2 = i & 63;
                float2 v = ((const float2*)(emb + (size_t)(kbase + ch2 * CH + code) * ND))[d2];
                es[d2 * 65 + code] = v;
            }
            __syncthreads();

            int k = kbase + ch2 * CH + cl;
            float a0 = 0.f, a1 = 0.f, a2 = 0.f, a3 = 0.f;
#pragma unroll
            for (int d2 = 0; d2 < 64; d2 += 2) {
                float2 zv0 = ze[d2 * RR + r];            // wave-uniform
                float2 ev0 = es[d2 * 65 + cl];           // conflict-free
                float2 zv1 = ze[(d2 + 1) * RR + r];
                float2 ev1 = es[(d2 + 1) * 65 + cl];
                a0 = fmaf(zv0.x, ev0.x, a0);
                a1 = fmaf(zv0.y, ev0.y, a1);
                a2 = fmaf(zv1.x, ev1.x, a2);
                a3 = fmaf(zv1.y, ev1.y, a3);
            }
            float s = fmaf(-2.0f, (a0 + a1) + (a2 + a3), enorm[k]);
            unsigned long long p = pack_si(s, k);
            bestp = (p < bestp) ? p : bestp;
        }

        // wave-reduce min (all lanes in this wave share the same row)
#pragma unroll
        for (int off = 32; off > 0; off >>= 1) {
            unsigned long long o = __shfl_down(bestp, off, 64);
            bestp = (o < bestp) ? o : bestp;
        }
        if (cl == 0) atomicMin(&rpart[row], bestp);
        __syncthreads();                 // protect ids/ze before next g
    }
}

// ---------------------------------------------------------------------------
// Kernel 4: rescue finalize — unpack winning idx per rescue row.
// ---------------------------------------------------------------------------
__global__ void rescue_fin_kernel(const int* __restrict__ rcount,
                                  const int* __restrict__ rlist,
                                  const unsigned long long* __restrict__ rpart,
                                  int* __restrict__ idx_out) {
    const int cnt = *rcount;
    for (int i = blockIdx.x * blockDim.x + threadIdx.x; i < cnt;
         i += gridDim.x * blockDim.x) {
        int row = rlist[i];
        idx_out[row] = (int)(rpart[row] & 0xffffffffull);
    }
}

// ---------------------------------------------------------------------------
// Kernel 5: gather + loss partial + transposed write (unchanged).
// ---------------------------------------------------------------------------
__global__ void out_kernel(const float* __restrict__ z,
                           const float* __restrict__ emb,
                           const int* __restrict__ idx,
                           float* __restrict__ out,
                           float* __restrict__ losspart) {
    __shared__ float zq[64 * 129];
    __shared__ int ids[64];
    __shared__ float redl[4];

    const int bid = blockIdx.x;
    const int b = bid >> 6;
    const int h = bid & 63;
    const int rowbase = bid * 64;
    const int t = threadIdx.x;

    if (t < 64) ids[t] = idx[rowbase + t];
    __syncthreads();

    const int d = t & 127;
    const int w0 = t >> 7;
    float lsum = 0.f;
#pragma unroll
    for (int wq = 0; wq < 32; wq++) {
        int w = w0 + 2 * wq;
        float e = emb[(size_t)ids[w] * ND + d];
        float zv = z[((size_t)(rowbase + w)) * ND + d];
        float df = e - zv;
        lsum = fmaf(df, df, lsum);
        zq[w * 129 + d] = e;
    }
#pragma unroll
    for (int off = 32; off > 0; off >>= 1) lsum += __shfl_down(lsum, off, 64);
    if ((t & 63) == 0) redl[t >> 6] = lsum;
    __syncthreads();
    if (t == 0) losspart[bid] = redl[0] + redl[1] + redl[2] + redl[3];

    const int w = t & 63;
    const int dq = t >> 6;
#pragma unroll
    for (int dd0 = 0; dd0 < 32; dd0++) {
        int dd = dq + 4 * dd0;
        out[(((size_t)b * ND + dd) * NH + h) * NW + w] = zq[w * 129 + dd];
    }
}

// ---------------------------------------------------------------------------
// Kernel 6: final loss reduce
// ---------------------------------------------------------------------------
__global__ void loss_kernel(const float* __restrict__ losspart,
                            float* __restrict__ out) {
    __shared__ float redl[4];
    const int t = threadIdx.x;
    float s = 0.f;
#pragma unroll
    for (int i = 0; i < 4; i++) s += losspart[t + 256 * i];
#pragma unroll
    for (int off = 32; off > 0; off >>= 1) s += __shfl_down(s, off, 64);
    if ((t & 63) == 0) redl[t >> 6] = s;
    __syncthreads();
    if (t == 0) {
        float total = redl[0] + redl[1] + redl[2] + redl[3];
        out[OUT_ELEMS] = 1.25f * total / (float)OUT_ELEMS;
    }
}

// ---------------------------------------------------------------------------
extern "C" void kernel_launch(void* const* d_in, const int* in_sizes, int n_in,
                              void* d_out, int out_size, void* d_ws, size_t ws_size,
                              hipStream_t stream) {
    const float* z = (const float*)d_in[0];      // [16,64,64,128] fp32
    const float* emb = (const float*)d_in[1];    // [4096,128] fp32
    float* out = (float*)d_out;                  // 8388608 + 1 fp32

    char* ws = (char*)d_ws;
    int* ws_idx = (int*)ws;                                         // 256 KB
    float* ws_enorm = (float*)(ws + (256 << 10));                   // 16 KB
    float* ws_losspart = (float*)(ws + (272 << 10));                // 4 KB
    int* ws_rcount = (int*)(ws + (276 << 10));                      // 1 KB
    int* ws_rlist = (int*)(ws + (277 << 10));                       // 256 KB
    unsigned short* ws_eh = (unsigned short*)(ws + (533 << 10));    // 1 MB
    unsigned long long* ws_rpart = (unsigned long long*)(ws + (1557 << 10)); // 512 KB

    hipMemsetAsync(ws_rcount, 0, sizeof(int), stream);
    emb_prep_kernel<<<NK / 4, 256, 0, stream>>>(emb, ws_enorm, ws_eh);
    mfma_argmin_kernel<<<NROWS / 64, 256, 0, stream>>>(z, ws_eh, ws_enorm,
                                                       ws_idx, ws_rcount,
                                                       ws_rlist, ws_rpart);
    rescue_kernel<<<2048, 256, 0, stream>>>(z, emb, ws_enorm, ws_rcount,
                                            ws_rlist, ws_rpart);
    rescue_fin_kernel<<<64, 256, 0, stream>>>(ws_rcount, ws_rlist, ws_rpart,
                                              ws_idx);
    out_kernel<<<NB * NH, 256, 0, stream>>>(z, emb, ws_idx, out, ws_losspart);
    loss_kernel<<<1, 256, 0, stream>>>(ws_losspart, out);
}